// Round 7
// baseline (623.764 us; speedup 1.0000x reference)
//
#include <hip/hip_runtime.h>
#include <hip/hip_bf16.h>

// Transformer block, B=2 T=2048 D=1024 H=16 DH=64 F=4096. fp32 in/out.
// R16 = R15 with occupancy fixed where it matters:
//  - FFN gemms: NT=1 (BN=32), grid 8x64 = 512 blocks = 2 blocks/CU.
//    Wo gemm: NT=2, grid 8x64 = 512 blocks. WAVE buffers resized
//    (NT1: NBUF=4 / 80KB, NT2: NBUF=3 / 72KB) so 2 blocks fit per CU ->
//    2 waves/SIMD of TLP to hide per-wave stalls (was 1 wave/SIMD).
//  - fattn: revert to R13 body (sequential paired q-tiles, no XCD swizzle,
//    T14 reg prefetch) — best measured (86.2 us). R15's merged pair
//    regressed (VGPR 104, serialized 2x proc between barriers).
//  - Memory layout, numerics identical to R15 (absmax 0.046875).

#define Bq_ 2
#define T_ 2048
#define D_ 1024
#define H_ 16
#define DH_ 64
#define F_ 4096
#define N_ (Bq_ * T_)   // 4096 rows
#define EPS_ 1e-5f
#define KP 72           // flash-attn LDS pitch

typedef __hip_bfloat16 bf16;
typedef unsigned short u16;
typedef __attribute__((ext_vector_type(8))) short bfrag;   // 8 bf16 = 4 VGPRs
typedef __attribute__((ext_vector_type(4))) float f32x4;

__device__ __forceinline__ u16 f2b(float f) {
    bf16 h = __float2bfloat16(f);
    return *(u16*)&h;
}
__device__ __forceinline__ float b2f_bits(u16 u) {
    return __uint_as_float(((unsigned)u) << 16);
}

// T2 swizzle: permute 16B (8xu16) blocks within each 32-u16 K-window by
// XOR with (row>>1)&3. Involution; preserves col&7 and col&~31.
__device__ __forceinline__ int swz(int row, int col) {
    return (col & ~31) | ((((col >> 3) ^ (row >> 1)) & 3) << 3) | (col & 7);
}

template <int N>
__device__ __forceinline__ void vmwait() {
    asm volatile("s_waitcnt vmcnt(%0)" :: "i"(N) : "memory");
}

#define GLDS16(g, l) __builtin_amdgcn_global_load_lds( \
    (const __attribute__((address_space(1))) unsigned int*)(g), \
    (__attribute__((address_space(3))) unsigned int*)(l), 16, 0, 0)

// XCD-aware block remap: blocks sharing an A-panel (same y, all gx x's)
// get linear ids ≡ same value (mod 8) -> dispatched to the same XCD.
// Requires gy % 8 == 0.
__device__ __forceinline__ void xcd_remap(int gx, int& bx, int& by) {
    const int bid = blockIdx.x + gx * blockIdx.y;
    const int t8 = bid >> 3;
    bx = t8 % gx;
    by = (bid & 7) + 8 * (t8 / gx);
}

// ---------------------------------------------------------------------------
// 64x64 fp32 transpose+cvt tile body -> bf16 dst rows drow0..+63 (swz'd).
__device__ __forceinline__ void tc_body(
    float (*Ts)[65], const float* s, int spitch,
    u16* dst, int dpitch, int drow0, int kcol0)
{
    const int t = threadIdx.x;
    #pragma unroll
    for (int i = 0; i < 4; i++) {
        const int idx = t + i * 256;
        const int kk = idx >> 4;
        const int mm = (idx & 15) * 4;
        float4 v = *(const float4*)(s + (size_t)kk * spitch + mm);
        Ts[mm][kk] = v.x; Ts[mm + 1][kk] = v.y;
        Ts[mm + 2][kk] = v.z; Ts[mm + 3][kk] = v.w;
    }
    __syncthreads();
    const int mm = t >> 2;
    const int kk0 = (t & 3) * 16;
    u16 o[16];
    #pragma unroll
    for (int j = 0; j < 16; j++) o[j] = f2b(Ts[mm][kk0 + j]);
    const int dr = drow0 + mm;
    u16* drow = dst + (size_t)dr * dpitch;
    const int c0 = kcol0 + kk0;
    *(uint4*)&drow[swz(dr, c0)]     = *(uint4*)&o[0];
    *(uint4*)&drow[swz(dr, c0 + 8)] = *(uint4*)&o[8];
}

// Generic tcvt (used for Wo): fp32 [K,M] slice -> bf16 [M,K] swz.
__global__ __launch_bounds__(256) void tcvt(
    const float* __restrict__ src, int spitch, int srow0, int scol0,
    u16* __restrict__ dst, int dpitch, int drow0)
{
    __shared__ float Ts[64][65];
    const int mb = blockIdx.x, kb = blockIdx.y;
    const float* s = src + (size_t)(srow0 + kb * 64) * spitch + scol0 + mb * 64;
    tc_body(Ts, s, spitch, dst, dpitch, drow0 + mb * 64, kb * 64);
}

// Fused Wk+Wv -> WkvT [2048][1024] swz. grid (1,16,32).
__global__ __launch_bounds__(256) void tcvt_kv(
    const float* __restrict__ Wk, const float* __restrict__ Wv,
    u16* __restrict__ dst)
{
    __shared__ float Ts[64][65];
    const int kb = blockIdx.y, z = blockIdx.z;
    const int sel = z >> 4, zz = z & 15;
    const float* src = sel ? Wv : Wk;
    const float* s = src + (size_t)zz * 1024 * 64 + (size_t)(kb * 64) * 64;
    tc_body(Ts, s, 64, dst, 1024, sel * 1024 + zz * 64, kb * 64);
}

// Fused FFN chunk transpose: z=0 -> W1 cols; z=1 -> W2 rows. grid (16,16,2).
__global__ __launch_bounds__(256) void tcvt_ffn(
    const float* __restrict__ W1, const float* __restrict__ W2, int c,
    u16* __restrict__ W1T, u16* __restrict__ W2T)
{
    __shared__ float Ts[64][65];
    const int mb = blockIdx.x, kb = blockIdx.y, z = blockIdx.z;
    const float* src = z ? W2 : W1;
    const int spitch = z ? 1024 : 4096;
    const int srow0  = z ? c * 1024 : 0;
    const int scol0  = z ? 0 : c * 1024;
    u16* dst = z ? W2T : W1T;
    const float* s = src + (size_t)(srow0 + kb * 64) * spitch + scol0 + mb * 64;
    tc_body(Ts, s, spitch, dst, 1024, mb * 64, kb * 64);
}

// ---------------------------------------------------------------------------
// cgemm: C[N, M] = A[N, lda] @ BT[M, Kdim]^T (+bias)(+relu)(+ACC), bf16 out.
// A: AF32 ? fp32 natural (cvt in reg; 2-phase barrier path)
//         : bf16 PRE-SWIZZLED (global_load_lds).
// BT: bf16 PRE-SWIZZLED, pitch=Kdim. Fragment reads XOR-swizzled.
// WAVE (requires !AF32): barrier-free wave-autonomous pipeline, wave-private
// buffers sized for 2 blocks/CU at NT<=2 (NT1: 80KB, NT2: 72KB).
template <int AF32, int SPLIT, int RELU, int ACC, int NT, int CSWZ, int WAVE>
__global__ __launch_bounds__(256) void cgemm(
    const void* __restrict__ A, int lda,
    const u16* __restrict__ BT,
    u16* __restrict__ C0, u16* __restrict__ C1, int ldc,
    int Kdim,
    const float* __restrict__ bias, int bias_off)
{
    static_assert(NT == 1 || NT == 2 || NT == 4, "NT");
    static_assert(!AF32 || NT == 4, "AF32 path assumes BN=128");
    static_assert(!(AF32 && WAVE), "WAVE requires glds-only staging");
    constexpr int BN = NT * 32;
    constexpr int NBUF = (NT == 1) ? 4 : ((NT == 2) ? 3 : 4);
    constexpr int DPT  = NBUF - 1;            // pipeline depth
    constexpr int LPT  = 4 + NT;              // glds per wave per tile
    constexpr int BELEM = 64 * 32;            // u16 per B slice
    constexpr int AELEM = NT * 16 * 32;       // u16 per A slice
    constexpr int PBUF  = BELEM + AELEM;
    constexpr int SELEM = WAVE ? 4 * NBUF * PBUF
                               : 2 * BN * 32 + 2 * 128 * 32;
    __shared__ alignas(16) u16 SMEM[SELEM];

    const int tid = threadIdx.x;
    const int lane = tid & 63;
    const int w = tid >> 6;
    const int lo16 = lane & 15;
    const int quad = lane >> 4;
    const int wi = w >> 1, wj = w & 1;

    int bx, by;
    xcd_remap(gridDim.x, bx, by);
    const int m0 = bx * 128;
    const int n0 = by * BN;

    f32x4 acc[NT][4] = {};

    const int c8 = (lane & 3) * 8;          // elem offset within row
    const int r4 = lane >> 2;               // row within a 16-row call
    // swizzled fragment column (row s-bits reduce to lane-only)
    const int fcol = ((quad ^ ((lo16 >> 1) & 3)) << 3);

    const int nsteps = Kdim >> 5;

    if constexpr (WAVE) {
        const u16* Ab = (const u16*)A;
        u16* wbase = &SMEM[w * NBUF * PBUF];
        auto wstage = [&](int slot, int k0) {
            u16* bb = wbase + slot * PBUF;
            #pragma unroll
            for (int c = 0; c < 4; c++)
                GLDS16(BT + (size_t)(m0 + wj * 64 + c * 16 + r4) * Kdim + k0 + c8,
                       bb + c * 512);
            u16* ab = bb + BELEM;
            #pragma unroll
            for (int c = 0; c < NT; c++)
                GLDS16(Ab + (size_t)(n0 + wi * (NT * 16) + c * 16 + r4) * lda + k0 + c8,
                       ab + c * 512);
        };
        #pragma unroll
        for (int i = 0; i < DPT; i++) wstage(i, i * 32);
        int t = 0, cb = 0;
        for (; t + DPT <= nsteps; ++t) {
            vmwait<(DPT - 1) * LPT>();
            __builtin_amdgcn_sched_barrier(0);
            const u16* bb = wbase + cb * PBUF;
            const u16* ab = bb + BELEM;
            bfrag af[NT], bfv[4];
            #pragma unroll
            for (int it = 0; it < NT; it++)
                af[it] = *(const bfrag*)(ab + (it * 16 + lo16) * 32 + fcol);
            #pragma unroll
            for (int jt = 0; jt < 4; jt++)
                bfv[jt] = *(const bfrag*)(bb + (jt * 16 + lo16) * 32 + fcol);
            if (t + DPT < nsteps)
                wstage(cb == 0 ? NBUF - 1 : cb - 1, (t + DPT) * 32);
            __builtin_amdgcn_s_setprio(1);
            #pragma unroll
            for (int it = 0; it < NT; it++)
                #pragma unroll
                for (int jt = 0; jt < 4; jt++)
                    acc[it][jt] = __builtin_amdgcn_mfma_f32_16x16x32_bf16(
                        af[it], bfv[jt], acc[it][jt], 0, 0, 0);
            __builtin_amdgcn_s_setprio(0);
            cb = (cb + 1 == NBUF) ? 0 : cb + 1;
        }
        vmwait<0>();
        __builtin_amdgcn_sched_barrier(0);
        for (; t < nsteps; ++t) {
            const u16* bb = wbase + cb * PBUF;
            const u16* ab = bb + BELEM;
            bfrag af[NT], bfv[4];
            #pragma unroll
            for (int it = 0; it < NT; it++)
                af[it] = *(const bfrag*)(ab + (it * 16 + lo16) * 32 + fcol);
            #pragma unroll
            for (int jt = 0; jt < 4; jt++)
                bfv[jt] = *(const bfrag*)(bb + (jt * 16 + lo16) * 32 + fcol);
            #pragma unroll
            for (int it = 0; it < NT; it++)
                #pragma unroll
                for (int jt = 0; jt < 4; jt++)
                    acc[it][jt] = __builtin_amdgcn_mfma_f32_16x16x32_bf16(
                        af[it], bfv[jt], acc[it][jt], 0, 0, 0);
            cb = (cb + 1 == NBUF) ? 0 : cb + 1;
        }
    } else {
        // 2-phase barrier path (AF32 only): shared As/Bs tiles.
        u16* As_ = SMEM;                    // [2][BN][32]
        u16* Bs_ = SMEM + 2 * BN * 32;      // [2][128][32]
        const int br0 = w * 32 + r4;
        const int br1 = br0 + 16;
        auto stage = [&](int buf, int k0) {
            GLDS16(BT + (size_t)(m0 + br0) * Kdim + k0 + c8,
                   Bs_ + buf * 128 * 32 + (w * 2 + 0) * 512);
            GLDS16(BT + (size_t)(m0 + br1) * Kdim + k0 + c8,
                   Bs_ + buf * 128 * 32 + (w * 2 + 1) * 512);
            const int ar = tid >> 1;
            const int kh = (tid & 1) * 16;
            const float* ap = (const float*)A + (size_t)(n0 + ar) * lda + k0 + kh;
            float4 v0 = ((const float4*)ap)[0];
            float4 v1 = ((const float4*)ap)[1];
            float4 v2 = ((const float4*)ap)[2];
            float4 v3 = ((const float4*)ap)[3];
            uint4 a0, a1;
            a0.x = (unsigned)f2b(v0.x) | ((unsigned)f2b(v0.y) << 16);
            a0.y = (unsigned)f2b(v0.z) | ((unsigned)f2b(v0.w) << 16);
            a0.z = (unsigned)f2b(v1.x) | ((unsigned)f2b(v1.y) << 16);
            a0.w = (unsigned)f2b(v1.z) | ((unsigned)f2b(v1.w) << 16);
            a1.x = (unsigned)f2b(v2.x) | ((unsigned)f2b(v2.y) << 16);
            a1.y = (unsigned)f2b(v2.z) | ((unsigned)f2b(v2.w) << 16);
            a1.z = (unsigned)f2b(v3.x) | ((unsigned)f2b(v3.y) << 16);
            a1.w = (unsigned)f2b(v3.z) | ((unsigned)f2b(v3.w) << 16);
            u16* arow = As_ + buf * BN * 32 + ar * 32;
            *(uint4*)&arow[swz(ar, kh)] = a0;
            *(uint4*)&arow[swz(ar, kh + 8)] = a1;
        };
        stage(0, 0);
        __syncthreads();
        int cur = 0;
        for (int t = 0; t < nsteps; ++t) {
            if (t + 1 < nsteps) stage(cur ^ 1, (t + 1) * 32);
            bfrag af[NT], bfv[4];
            #pragma unroll
            for (int it = 0; it < NT; it++)
                af[it] = *(const bfrag*)(As_ + cur * BN * 32
                         + (wi * (NT * 16) + it * 16 + lo16) * 32 + fcol);
            #pragma unroll
            for (int jt = 0; jt < 4; jt++)
                bfv[jt] = *(const bfrag*)(Bs_ + cur * 128 * 32
                          + (wj * 64 + jt * 16 + lo16) * 32 + fcol);
            __builtin_amdgcn_s_setprio(1);
            #pragma unroll
            for (int it = 0; it < NT; it++)
                #pragma unroll
                for (int jt = 0; jt < 4; jt++)
                    acc[it][jt] = __builtin_amdgcn_mfma_f32_16x16x32_bf16(
                        af[it], bfv[jt], acc[it][jt], 0, 0, 0);
            __builtin_amdgcn_s_setprio(0);
            if (t + 1 < nsteps) {
                __syncthreads();
                cur ^= 1;
            }
        }
    }
    // ---- epilogue ----
    #pragma unroll
    for (int jt = 0; jt < 4; jt++) {
        const int col = m0 + wj * 64 + jt * 16 + lo16;
        u16* Cp;
        int cc;
        if constexpr (SPLIT) {
            Cp = (col >> 10) ? C1 : C0;
            cc = col & 1023;
        } else {
            Cp = C0;
            cc = col;
        }
        const float bv = bias ? bias[bias_off + col] : 0.f;
        #pragma unroll
        for (int it = 0; it < NT; it++) {
            #pragma unroll
            for (int r = 0; r < 4; r++) {
                const int row = n0 + wi * (NT * 16) + it * 16 + quad * 4 + r;
                float v = acc[it][jt][r] + bv;
                if constexpr (RELU) v = fmaxf(v, 0.f);
                const int ccs = CSWZ ? swz(row, cc) : cc;
                u16* cp = Cp + (size_t)row * ldc + ccs;
                if constexpr (ACC) v += b2f_bits(*cp);
                *cp = f2b(v);
            }
        }
    }
}

// ---------------------------------------------------------------------------
// Old fp32-staging GEMM, kept only for the Q projection. XCD remap.
template <int AF32, int QKV, int RELU, int ACC>
__global__ __launch_bounds__(256) void mgemm(
    const void* __restrict__ A,
    const float* __restrict__ B0f, const float* __restrict__ B1f, const float* __restrict__ B2f,
    u16* __restrict__ C0, u16* __restrict__ C1, u16* __restrict__ C2,
    int ldb, int brow_off, int bcol_off,
    const float* __restrict__ bias, int bias_off)
{
    __shared__ alignas(16) u16 As[128][32];
    __shared__ alignas(16) u16 Bt[128][40];
    __shared__ alignas(16) float Bs32[32][132];

    const int tid = threadIdx.x;
    const int lane = tid & 63;
    const int w = tid >> 6;
    const int lo16 = lane & 15;
    const int quad = lane >> 4;
    const int wi = w >> 1, wj = w & 1;

    int bx, by;
    xcd_remap(gridDim.x, bx, by);
    const int m0 = bx * 128;
    const int n0 = by * 128;

    f32x4 acc[4][4] = {};

    const int ar  = tid >> 1;
    const int akh = (tid & 1) * 16;
    const int bmq = tid & 31;
    const int bkb = (tid >> 5) * 4;
    const int tm  = tid >> 1;
    const int tkh = (tid & 1) * 16;

    for (int k0 = 0; k0 < 1024; k0 += 32) {
        uint4 a0, a1;
        if constexpr (AF32) {
            const float* ap = (const float*)A + (size_t)(n0 + ar) * 1024 + k0 + akh;
            float4 v0 = ((const float4*)ap)[0];
            float4 v1 = ((const float4*)ap)[1];
            float4 v2 = ((const float4*)ap)[2];
            float4 v3 = ((const float4*)ap)[3];
            a0.x = (unsigned)f2b(v0.x) | ((unsigned)f2b(v0.y) << 16);
            a0.y = (unsigned)f2b(v0.z) | ((unsigned)f2b(v0.w) << 16);
            a0.z = (unsigned)f2b(v1.x) | ((unsigned)f2b(v1.y) << 16);
            a0.w = (unsigned)f2b(v1.z) | ((unsigned)f2b(v1.w) << 16);
            a1.x = (unsigned)f2b(v2.x) | ((unsigned)f2b(v2.y) << 16);
            a1.y = (unsigned)f2b(v2.z) | ((unsigned)f2b(v2.w) << 16);
            a1.z = (unsigned)f2b(v3.x) | ((unsigned)f2b(v3.y) << 16);
            a1.w = (unsigned)f2b(v3.z) | ((unsigned)f2b(v3.w) << 16);
        } else {
            const u16* ap = (const u16*)A + (size_t)(n0 + ar) * 1024 + k0 + akh;
            a0 = ((const uint4*)ap)[0];
            a1 = ((const uint4*)ap)[1];
        }
        #pragma unroll
        for (int kk = 0; kk < 4; kk++) {
            const int k = bkb + kk;
            const float* bp;
            if constexpr (QKV) {
                const int m = m0 + bmq * 4;
                const int sel = m >> 10;
                const int mm = m & 1023;
                const float* Wp = (sel == 0) ? B0f : ((sel == 1) ? B1f : B2f);
                bp = Wp + ((size_t)(mm >> 6) * 1024 + k0 + k) * 64 + (mm & 63);
            } else {
                bp = B0f + (size_t)(brow_off + k0 + k) * ldb + bcol_off + m0 + bmq * 4;
            }
            *(float4*)&Bs32[k][bmq * 4] = *(const float4*)bp;
        }
        __syncthreads();
        *(uint4*)&As[ar][akh] = a0;
        *(uint4*)&As[ar][akh + 8] = a1;
        {
            u16 t[16];
            #pragma unroll
            for (int i = 0; i < 16; i++) t[i] = f2b(Bs32[tkh + i][tm]);
            *(uint4*)&Bt[tm][tkh] = *(uint4*)&t[0];
            *(uint4*)&Bt[tm][tkh + 8] = *(uint4*)&t[8];
        }
        __syncthreads();
        bfrag af[4], bfv[4];
        #pragma unroll
        for (int it = 0; it < 4; it++)
            af[it] = *(const bfrag*)&As[wi * 64 + it * 16 + lo16][quad * 8];
        #pragma unroll
        for (int jt = 0; jt < 4; jt++)
            bfv[jt] = *(const bfrag*)&Bt[wj * 64 + jt * 16 + lo16][quad * 8];
        #pragma unroll
        for (int it = 0; it < 4; it++)
            #pragma unroll
            for (int jt = 0; jt < 4; jt++)
                acc[it][jt] = __builtin_amdgcn_mfma_f32_16x16x32_bf16(
                    af[it], bfv[jt], acc[it][jt], 0, 0, 0);
        __syncthreads();
    }
    #pragma unroll
    for (int jt = 0; jt < 4; jt++) {
        const int col = m0 + wj * 64 + jt * 16 + lo16;
        u16* Cp;
        int cc;
        if constexpr (QKV) {
            const int sel = col >> 10;
            cc = col & 1023;
            Cp = (sel == 0) ? C0 : ((sel == 1) ? C1 : C2);
        } else {
            Cp = C0;
            cc = col;
        }
        const float bv = bias ? bias[bias_off + col] : 0.f;
        #pragma unroll
        for (int it = 0; it < 4; it++) {
            #pragma unroll
            for (int r = 0; r < 4; r++) {
                const int row = n0 + wi * 64 + it * 16 + quad * 4 + r;
                float v = acc[it][jt][r] + bv;
                if constexpr (RELU) v = fmaxf(v, 0.f);
                u16* cp = Cp + (size_t)row * 1024 + cc;
                if constexpr (ACC) v += b2f_bits(*cp);
                *cp = f2b(v);
            }
        }
    }
}

// Flash attention (R13 body, best measured 86.2us): paired q-tiles
// (qp, 31-qp) processed SEQUENTIALLY, 512 blocks x 33 KV-tiles uniform.
// T14 reg prefetch per q-tile. No XCD swizzle. O written PRE-SWIZZLED.
__global__ __launch_bounds__(256) void fattn_kernel(
    u16* __restrict__ Q, const u16* __restrict__ Kg, const u16* __restrict__ Vg)
{
    const int bi = blockIdx.x;
    const int qp = bi & 15;
    const int h  = (bi >> 4) & 15;
    const int b  = bi >> 8;
    const int tid = threadIdx.x;
    const int w = tid >> 6;
    const int lane = tid & 63;
    const int lo16 = lane & 15;
    const int quad = lane >> 4;

    __shared__ alignas(16) u16 Ks[64][KP];
    __shared__ alignas(16) u16 Vt[64][KP];
    __shared__ alignas(16) u16 Ps[4][16][KP];

    const int sr = tid >> 2;
    const int ec = (tid & 3) * 16;

    #pragma unroll 1
    for (int pi = 0; pi < 2; pi++) {
        const int qt = pi ? (31 - qp) : qp;
        const int q0 = qt * 64;
        const size_t qrow = (size_t)(b * T_ + q0 + w * 16 + lo16) * 1024 + h * 64;
        bfrag qa0 = *(const bfrag*)(Q + qrow + quad * 8);
        bfrag qa1 = *(const bfrag*)(Q + qrow + 32 + quad * 8);

        f32x4 oacc[4] = {};
        float m_r[4], l_r[4];
        #pragma unroll
        for (int r = 0; r < 4; r++) { m_r[r] = -3e38f; l_r[r] = 0.f; }

        uint4 ka, kb, va, vb;
        {
            const size_t grow = (size_t)(b * T_ + sr) * 1024 + h * 64 + ec;
            ka = *(const uint4*)(Kg + grow);
            kb = *(const uint4*)(Kg + grow + 8);
            va = *(const uint4*)(Vg + grow);
            vb = *(const uint4*)(Vg + grow + 8);
        }

        for (int st = 0; st <= qt; st++) {
            *(uint4*)&Ks[sr][ec] = ka;
            *(uint4*)&Ks[sr][ec + 8] = kb;
            {
                unsigned vv[8] = {va.x, va.y, va.z, va.w, vb.x, vb.y, vb.z, vb.w};
                #pragma unroll
                for (int k2 = 0; k2 < 8; k2++) {
                    Vt[ec + 2 * k2][sr]     = (u16)(vv[k2] & 0xffff);
                    Vt[ec + 2 * k2 + 1][sr] = (u16)(vv[k2] >> 16);
                }
            }
            __syncthreads();
            if (st < qt) {
                const size_t grow = (size_t)(b * T_ + (st + 1) * 64 + sr) * 1024
                                  + h * 64 + ec;
                ka = *(const uint4*)(Kg + grow);
                kb = *(const uint4*)(Kg + grow + 8);
                va = *(const uint4*)(Vg + grow);
                vb = *(const uint4*)(Vg + grow + 8);
            }

            float sv[4][4];
            #pragma unroll
            for (int nt = 0; nt < 4; nt++) {
                bfrag kb0 = *(const bfrag*)&Ks[nt * 16 + lo16][quad * 8];
                bfrag kb1 = *(const bfrag*)&Ks[nt * 16 + lo16][32 + quad * 8];
                f32x4 cs = {0.f, 0.f, 0.f, 0.f};
                cs = __builtin_amdgcn_mfma_f32_16x16x32_bf16(qa0, kb0, cs, 0, 0, 0);
                cs = __builtin_amdgcn_mfma_f32_16x16x32_bf16(qa1, kb1, cs, 0, 0, 0);
                #pragma unroll
                for (int r = 0; r < 4; r++) sv[nt][r] = cs[r] * 0.125f;
            }
            if (st == qt) {
                #pragma unroll
                for (int nt = 0; nt < 4; nt++)
                    #pragma unroll
                    for (int r = 0; r < 4; r++)
                        if (nt * 16 + lo16 > w * 16 + quad * 4 + r) sv[nt][r] = -3e38f;
            }
            #pragma unroll
            for (int r = 0; r < 4; r++) {
                float m = fmaxf(fmaxf(sv[0][r], sv[1][r]), fmaxf(sv[2][r], sv[3][r]));
                #pragma unroll
                for (int off = 1; off < 16; off <<= 1)
                    m = fmaxf(m, __shfl_xor(m, off, 64));
                float mnew = fmaxf(m_r[r], m);
                float alpha = __expf(m_r[r] - mnew);
                m_r[r] = mnew;
                float s = 0.f;
                #pragma unroll
                for (int nt = 0; nt < 4; nt++) {
                    sv[nt][r] = __expf(sv[nt][r] - mnew);
                    s += sv[nt][r];
                }
                #pragma unroll
                for (int off = 1; off < 16; off <<= 1)
                    s += __shfl_xor(s, off, 64);
                l_r[r] = l_r[r] * alpha + s;
                #pragma unroll
                for (int et = 0; et < 4; et++) oacc[et][r] *= alpha;
            }
            #pragma unroll
            for (int nt = 0; nt < 4; nt++)
                #pragma unroll
                for (int r = 0; r < 4; r++)
                    Ps[w][quad * 4 + r][nt * 16 + lo16] = f2b(sv[nt][r]);
            bfrag pa0 = *(const bfrag*)&Ps[w][lo16][quad * 8];
            bfrag pa1 = *(const bfrag*)&Ps[w][lo16][32 + quad * 8];
            #pragma unroll
            for (int et = 0; et < 4; et++) {
                bfrag vb0 = *(const bfrag*)&Vt[et * 16 + lo16][quad * 8];
                bfrag vb1 = *(const bfrag*)&Vt[et * 16 + lo16][32 + quad * 8];
                oacc[et] = __builtin_amdgcn_mfma_f32_16x16x32_bf16(pa0, vb0, oacc[et], 0, 0, 0);
                oacc[et] = __builtin_amdgcn_mfma_f32_16x16x32_bf16(pa1, vb1, oacc[et], 0, 0, 0);
            }
            __syncthreads();
        }
        #pragma unroll
        for (int r = 0; r < 4; r++) {
            float rl = 1.f / l_r[r];
            const int row = q0 + w * 16 + quad * 4 + r;
            u16* orow = Q + (size_t)(b * T_ + row) * 1024;
            #pragma unroll
            for (int et = 0; et < 4; et++)
                orow[swz(row, h * 64 + et * 16 + lo16)] = f2b(oacc[et][r] * rl);
        }
    }
}

// LN(src bf16)*g + be + resid(fp32). WF32=1 -> fp32 dstf, else bf16 dstb
// (OSWZ: bf16 output written pre-swizzled for cgemm A consumption).
template <int WF32, int OSWZ>
__global__ __launch_bounds__(256) void ln_kernel(
    const u16* __restrict__ src, const float* __restrict__ resid,
    const float* __restrict__ g, const float* __restrict__ be,
    u16* __restrict__ dstb, float* __restrict__ dstf)
{
    const int r = blockIdx.x;
    const int tid = threadIdx.x;
    uint2 raw = ((const uint2*)(src + (size_t)r * D_))[tid];
    float y[4];
    y[0] = __uint_as_float(raw.x << 16);
    y[1] = __uint_as_float(raw.x & 0xffff0000u);
    y[2] = __uint_as_float(raw.y << 16);
    y[3] = __uint_as_float(raw.y & 0xffff0000u);
    float s = y[0] + y[1] + y[2] + y[3];
    float sq = y[0]*y[0] + y[1]*y[1] + y[2]*y[2] + y[3]*y[3];
    #pragma unroll
    for (int o = 32; o > 0; o >>= 1) {
        s += __shfl_down(s, o, 64);
        sq += __shfl_down(sq, o, 64);
    }
    __shared__ float rs[4], rq[4];
    if ((tid & 63) == 0) { rs[tid >> 6] = s; rq[tid >> 6] = sq; }
    __syncthreads();
    const float S = rs[0] + rs[1] + rs[2] + rs[3];
    const float Qm = rq[0] + rq[1] + rq[2] + rq[3];
    const float mu = S * (1.f / (float)D_);
    const float var = fmaxf(Qm * (1.f / (float)D_) - mu * mu, 0.f);
    const float rstd = rsqrtf(var + EPS_);
    const int c = tid * 4;
    #pragma unroll
    for (int i = 0; i < 4; i++) {
        y[i] = (y[i] - mu) * rstd * g[c + i] + be[c + i]
             + resid[(size_t)r * D_ + c + i];
    }
    if constexpr (WF32) {
        float4 o = {y[0], y[1], y[2], y[3]};
        ((float4*)(dstf + (size_t)r * D_))[tid] = o;
    } else {
        uint2 o;
        o.x = (unsigned)f2b(y[0]) | ((unsigned)f2b(y[1]) << 16);
        o.y = (unsigned)f2b(y[2]) | ((unsigned)f2b(y[3]) << 16);
        const int cs = OSWZ ? swz(r, c) : c;
        *(uint2*)(dstb + (size_t)r * D_ + cs) = o;
    }
}

extern "C" void kernel_launch(void* const* d_in, const int* in_sizes, int n_in,
                              void* d_out, int out_size, void* d_ws, size_t ws_size,
                              hipStream_t stream)
{
    const float* emb = (const float*)d_in[0];
    const float* Wq  = (const float*)d_in[1];
    const float* Wk  = (const float*)d_in[2];
    const float* Wv  = (const float*)d_in[3];
    const float* Wo  = (const float*)d_in[4];
    const float* bo  = (const float*)d_in[5];
    const float* W1  = (const float*)d_in[6];
    const float* b1  = (const float*)d_in[7];
    const float* W2  = (const float*)d_in[8];
    const float* b2  = (const float*)d_in[9];
    const float* g1  = (const float*)d_in[10];
    const float* be1 = (const float*)d_in[11];
    const float* g2  = (const float*)d_in[12];
    const float* be2 = (const float*)d_in[13];

    u16* WS = (u16*)d_ws;       // 4M u16
    u16* DO = (u16*)d_out;      // 8M u16

    const size_t M1 = 1024 * 1024;
    u16* WkvT = WS;                      // [2048][1024] bf16 swz (4MB)
    u16* Q    = WS;                      // natural (over dead WkvT)
    u16* Kb   = DO;                      // [0,4M) natural
    u16* Vb   = DO + 4 * M1;             // [4M,8M) natural
    u16* O    = WS;                      // fattn writes O (swz) over Q
    u16* WoT  = DO;                      // [0,1M) swz, over dead K
    u16* P    = DO + 4 * M1;             // [4M,8M) natural, over dead V
    u16* Af   = DO;                      // [0,4M) swz, over dead WoT
    u16* Hc   = DO + 4 * M1;             // [4M,6M) [2048][1024] swz
    u16* W1T  = DO + 6 * M1;             // [6M,7M) swz
    u16* W2T  = DO + 7 * M1;             // [7M,8M) swz
    u16* F    = WS;                      // natural, over dead O
    float* outf = (float*)d_out;

    const dim3 blk(256);

    // 1) Wk,Wv -> WkvT bf16 swz (one launch)
    tcvt_kv<<<dim3(1, 16, 32), blk, 0, stream>>>(Wk, Wv, WkvT);
    // 2) K,V = emb @ WkvT^T  (A fp32, split output, natural C; 2-phase)
    cgemm<1, 1, 0, 0, 4, 0, 0><<<dim3(16, 32), blk, 0, stream>>>(
        emb, 1024, WkvT, Kb, Vb, 1024, 1024, nullptr, 0);
    // 3) Q = emb @ Wq (old fp32-staging path, natural)
    mgemm<1, 1, 0, 0><<<dim3(8, 32), blk, 0, stream>>>(
        emb, Wq, Wq, Wq, Q, nullptr, nullptr, 0, 0, 0, nullptr, 0);
    // 4) flash attention (R13 body), O (swz) over Q
    fattn_kernel<<<Bq_ * H_ * 16, blk, 0, stream>>>(Q, Kb, Vb);
    // 5) Wo -> WoT bf16 swz (over dead K)
    tcvt<<<dim3(16, 16), blk, 0, stream>>>(Wo, 1024, 0, 0, WoT, 1024, 0);
    // 6) P = O @ WoT^T + bo (natural C, over dead V; WAVE NT=2, 512 blocks)
    cgemm<0, 0, 0, 0, 2, 0, 1><<<dim3(8, 64), blk, 0, stream>>>(
        O, 1024, WoT, P, nullptr, 1024, 1024, bo, 0);
    // 7) Af = LN(P) + emb (swz out)
    ln_kernel<0, 1><<<N_, blk, 0, stream>>>(P, emb, g1, be1, Af, nullptr);
    // 8) FFN: 4 hidden chunks x 2 row-halves; NT=1, 512-block grids
    for (int c = 0; c < 4; c++) {
        tcvt_ffn<<<dim3(16, 16, 2), blk, 0, stream>>>(W1, W2, c, W1T, W2T);
        for (int rh = 0; rh < 2; rh++) {
            u16* Afh = Af + (size_t)rh * 2048 * 1024;
            u16* Fh  = F  + (size_t)rh * 2048 * 1024;
            cgemm<0, 0, 1, 0, 1, 1, 1><<<dim3(8, 64), blk, 0, stream>>>(
                Afh, 1024, W1T, Hc, nullptr, 1024, 1024, b1, c * 1024);
            if (c == 0) {
                cgemm<0, 0, 0, 0, 1, 0, 1><<<dim3(8, 64), blk, 0, stream>>>(
                    Hc, 1024, W2T, Fh, nullptr, 1024, 1024, b2, 0);
            } else {
                cgemm<0, 0, 0, 1, 1, 0, 1><<<dim3(8, 64), blk, 0, stream>>>(
                    Hc, 1024, W2T, Fh, nullptr, 1024, 1024, nullptr, 0);
            }
        }
    }
    // 9) out = fp32(LN(F) + emb)
    ln_kernel<1, 0><<<N_, blk, 0, stream>>>(F, emb, g2, be2, nullptr, outf);
}

// Round 8
// 548.024 us; speedup vs baseline: 1.1382x; 1.1382x over previous
//
#include <hip/hip_runtime.h>
#include <hip/hip_bf16.h>

// Transformer block, B=2 T=2048 D=1024 H=16 DH=64 F=4096. fp32 in/out.
// R17 = best-of-measured recombination:
//  - GEMM path: exact R15 config (best measured, 446us): Wo NT=4 NBUF=4,
//    FFN NT=2 NBUF=5, KV AF32 2-phase, Q mgemm; XCD remap everywhere;
//    wave-autonomous barrier-free pipelines at depth 3-4, 1 block/CU.
//    (R16's NT=1 / NBUF=3 regressed: halved arithmetic intensity and
//    pipeline depth — staging traffic and lead time both got worse.)
//  - fattn: R13/R16 body (best measured, 86.8us): sequential paired
//    q-tiles (qp, 31-qp), 512 blocks x 33 KV-tiles uniform, T14 reg
//    prefetch, NO XCD swizzle (R14 showed swizzle costs ~6us here).
//  - Numerics identical to R11-R16 (verified absmax 0.046875).

#define Bq_ 2
#define T_ 2048
#define D_ 1024
#define H_ 16
#define DH_ 64
#define F_ 4096
#define N_ (Bq_ * T_)   // 4096 rows
#define EPS_ 1e-5f
#define KP 72           // flash-attn LDS pitch

typedef __hip_bfloat16 bf16;
typedef unsigned short u16;
typedef __attribute__((ext_vector_type(8))) short bfrag;   // 8 bf16 = 4 VGPRs
typedef __attribute__((ext_vector_type(4))) float f32x4;

__device__ __forceinline__ u16 f2b(float f) {
    bf16 h = __float2bfloat16(f);
    return *(u16*)&h;
}
__device__ __forceinline__ float b2f_bits(u16 u) {
    return __uint_as_float(((unsigned)u) << 16);
}

// T2 swizzle: permute 16B (8xu16) blocks within each 32-u16 K-window by
// XOR with (row>>1)&3. Involution; preserves col&7 and col&~31.
__device__ __forceinline__ int swz(int row, int col) {
    return (col & ~31) | ((((col >> 3) ^ (row >> 1)) & 3) << 3) | (col & 7);
}

template <int N>
__device__ __forceinline__ void vmwait() {
    asm volatile("s_waitcnt vmcnt(%0)" :: "i"(N) : "memory");
}

#define GLDS16(g, l) __builtin_amdgcn_global_load_lds( \
    (const __attribute__((address_space(1))) unsigned int*)(g), \
    (__attribute__((address_space(3))) unsigned int*)(l), 16, 0, 0)

// XCD-aware block remap: blocks sharing an A-panel (same y, all gx x's)
// get linear ids ≡ same value (mod 8) -> dispatched to the same XCD.
// Requires gy % 8 == 0.
__device__ __forceinline__ void xcd_remap(int gx, int& bx, int& by) {
    const int bid = blockIdx.x + gx * blockIdx.y;
    const int t8 = bid >> 3;
    bx = t8 % gx;
    by = (bid & 7) + 8 * (t8 / gx);
}

// ---------------------------------------------------------------------------
// 64x64 fp32 transpose+cvt tile body -> bf16 dst rows drow0..+63 (swz'd).
__device__ __forceinline__ void tc_body(
    float (*Ts)[65], const float* s, int spitch,
    u16* dst, int dpitch, int drow0, int kcol0)
{
    const int t = threadIdx.x;
    #pragma unroll
    for (int i = 0; i < 4; i++) {
        const int idx = t + i * 256;
        const int kk = idx >> 4;
        const int mm = (idx & 15) * 4;
        float4 v = *(const float4*)(s + (size_t)kk * spitch + mm);
        Ts[mm][kk] = v.x; Ts[mm + 1][kk] = v.y;
        Ts[mm + 2][kk] = v.z; Ts[mm + 3][kk] = v.w;
    }
    __syncthreads();
    const int mm = t >> 2;
    const int kk0 = (t & 3) * 16;
    u16 o[16];
    #pragma unroll
    for (int j = 0; j < 16; j++) o[j] = f2b(Ts[mm][kk0 + j]);
    const int dr = drow0 + mm;
    u16* drow = dst + (size_t)dr * dpitch;
    const int c0 = kcol0 + kk0;
    *(uint4*)&drow[swz(dr, c0)]     = *(uint4*)&o[0];
    *(uint4*)&drow[swz(dr, c0 + 8)] = *(uint4*)&o[8];
}

// Generic tcvt (used for Wo): fp32 [K,M] slice -> bf16 [M,K] swz.
__global__ __launch_bounds__(256) void tcvt(
    const float* __restrict__ src, int spitch, int srow0, int scol0,
    u16* __restrict__ dst, int dpitch, int drow0)
{
    __shared__ float Ts[64][65];
    const int mb = blockIdx.x, kb = blockIdx.y;
    const float* s = src + (size_t)(srow0 + kb * 64) * spitch + scol0 + mb * 64;
    tc_body(Ts, s, spitch, dst, dpitch, drow0 + mb * 64, kb * 64);
}

// Fused Wk+Wv -> WkvT [2048][1024] swz. grid (1,16,32).
__global__ __launch_bounds__(256) void tcvt_kv(
    const float* __restrict__ Wk, const float* __restrict__ Wv,
    u16* __restrict__ dst)
{
    __shared__ float Ts[64][65];
    const int kb = blockIdx.y, z = blockIdx.z;
    const int sel = z >> 4, zz = z & 15;
    const float* src = sel ? Wv : Wk;
    const float* s = src + (size_t)zz * 1024 * 64 + (size_t)(kb * 64) * 64;
    tc_body(Ts, s, 64, dst, 1024, sel * 1024 + zz * 64, kb * 64);
}

// Fused FFN chunk transpose: z=0 -> W1 cols; z=1 -> W2 rows. grid (16,16,2).
__global__ __launch_bounds__(256) void tcvt_ffn(
    const float* __restrict__ W1, const float* __restrict__ W2, int c,
    u16* __restrict__ W1T, u16* __restrict__ W2T)
{
    __shared__ float Ts[64][65];
    const int mb = blockIdx.x, kb = blockIdx.y, z = blockIdx.z;
    const float* src = z ? W2 : W1;
    const int spitch = z ? 1024 : 4096;
    const int srow0  = z ? c * 1024 : 0;
    const int scol0  = z ? 0 : c * 1024;
    u16* dst = z ? W2T : W1T;
    const float* s = src + (size_t)(srow0 + kb * 64) * spitch + scol0 + mb * 64;
    tc_body(Ts, s, spitch, dst, 1024, mb * 64, kb * 64);
}

// ---------------------------------------------------------------------------
// cgemm: C[N, M] = A[N, lda] @ BT[M, Kdim]^T (+bias)(+relu)(+ACC), bf16 out.
// A: AF32 ? fp32 natural (cvt in reg; 2-phase barrier path)
//         : bf16 PRE-SWIZZLED (global_load_lds).
// BT: bf16 PRE-SWIZZLED, pitch=Kdim. Fragment reads XOR-swizzled.
// WAVE (requires !AF32): barrier-free wave-autonomous pipeline, wave-private
// buffers (NT2: NBUF=5/120KB depth-4, NT4: NBUF=4/128KB depth-3).
template <int AF32, int SPLIT, int RELU, int ACC, int NT, int CSWZ, int WAVE>
__global__ __launch_bounds__(256) void cgemm(
    const void* __restrict__ A, int lda,
    const u16* __restrict__ BT,
    u16* __restrict__ C0, u16* __restrict__ C1, int ldc,
    int Kdim,
    const float* __restrict__ bias, int bias_off)
{
    static_assert(NT == 2 || NT == 4, "NT");
    static_assert(!AF32 || NT == 4, "AF32 path assumes BN=128");
    static_assert(!(AF32 && WAVE), "WAVE requires glds-only staging");
    constexpr int BN = NT * 32;
    constexpr int NBUF = (NT == 2) ? 5 : 4;   // wave-private buffers
    constexpr int DPT  = NBUF - 1;            // pipeline depth
    constexpr int LPT  = 4 + NT;              // glds per wave per tile
    constexpr int BELEM = 64 * 32;            // u16 per B slice
    constexpr int AELEM = NT * 16 * 32;       // u16 per A slice
    constexpr int PBUF  = BELEM + AELEM;
    constexpr int SELEM = WAVE ? 4 * NBUF * PBUF
                               : 2 * BN * 32 + 2 * 128 * 32;
    __shared__ alignas(16) u16 SMEM[SELEM];

    const int tid = threadIdx.x;
    const int lane = tid & 63;
    const int w = tid >> 6;
    const int lo16 = lane & 15;
    const int quad = lane >> 4;
    const int wi = w >> 1, wj = w & 1;

    int bx, by;
    xcd_remap(gridDim.x, bx, by);
    const int m0 = bx * 128;
    const int n0 = by * BN;

    f32x4 acc[NT][4] = {};

    const int c8 = (lane & 3) * 8;          // elem offset within row
    const int r4 = lane >> 2;               // row within a 16-row call
    // swizzled fragment column (row s-bits reduce to lane-only)
    const int fcol = ((quad ^ ((lo16 >> 1) & 3)) << 3);

    const int nsteps = Kdim >> 5;

    if constexpr (WAVE) {
        const u16* Ab = (const u16*)A;
        u16* wbase = &SMEM[w * NBUF * PBUF];
        auto wstage = [&](int slot, int k0) {
            u16* bb = wbase + slot * PBUF;
            #pragma unroll
            for (int c = 0; c < 4; c++)
                GLDS16(BT + (size_t)(m0 + wj * 64 + c * 16 + r4) * Kdim + k0 + c8,
                       bb + c * 512);
            u16* ab = bb + BELEM;
            #pragma unroll
            for (int c = 0; c < NT; c++)
                GLDS16(Ab + (size_t)(n0 + wi * (NT * 16) + c * 16 + r4) * lda + k0 + c8,
                       ab + c * 512);
        };
        #pragma unroll
        for (int i = 0; i < DPT; i++) wstage(i, i * 32);
        int t = 0, cb = 0;
        for (; t + DPT <= nsteps; ++t) {
            vmwait<(DPT - 1) * LPT>();
            __builtin_amdgcn_sched_barrier(0);
            const u16* bb = wbase + cb * PBUF;
            const u16* ab = bb + BELEM;
            bfrag af[NT], bfv[4];
            #pragma unroll
            for (int it = 0; it < NT; it++)
                af[it] = *(const bfrag*)(ab + (it * 16 + lo16) * 32 + fcol);
            #pragma unroll
            for (int jt = 0; jt < 4; jt++)
                bfv[jt] = *(const bfrag*)(bb + (jt * 16 + lo16) * 32 + fcol);
            if (t + DPT < nsteps)
                wstage(cb == 0 ? NBUF - 1 : cb - 1, (t + DPT) * 32);
            __builtin_amdgcn_s_setprio(1);
            #pragma unroll
            for (int it = 0; it < NT; it++)
                #pragma unroll
                for (int jt = 0; jt < 4; jt++)
                    acc[it][jt] = __builtin_amdgcn_mfma_f32_16x16x32_bf16(
                        af[it], bfv[jt], acc[it][jt], 0, 0, 0);
            __builtin_amdgcn_s_setprio(0);
            cb = (cb + 1 == NBUF) ? 0 : cb + 1;
        }
        vmwait<0>();
        __builtin_amdgcn_sched_barrier(0);
        for (; t < nsteps; ++t) {
            const u16* bb = wbase + cb * PBUF;
            const u16* ab = bb + BELEM;
            bfrag af[NT], bfv[4];
            #pragma unroll
            for (int it = 0; it < NT; it++)
                af[it] = *(const bfrag*)(ab + (it * 16 + lo16) * 32 + fcol);
            #pragma unroll
            for (int jt = 0; jt < 4; jt++)
                bfv[jt] = *(const bfrag*)(bb + (jt * 16 + lo16) * 32 + fcol);
            #pragma unroll
            for (int it = 0; it < NT; it++)
                #pragma unroll
                for (int jt = 0; jt < 4; jt++)
                    acc[it][jt] = __builtin_amdgcn_mfma_f32_16x16x32_bf16(
                        af[it], bfv[jt], acc[it][jt], 0, 0, 0);
            cb = (cb + 1 == NBUF) ? 0 : cb + 1;
        }
    } else {
        // 2-phase barrier path (AF32 only): shared As/Bs tiles.
        u16* As_ = SMEM;                    // [2][BN][32]
        u16* Bs_ = SMEM + 2 * BN * 32;      // [2][128][32]
        const int br0 = w * 32 + r4;
        const int br1 = br0 + 16;
        auto stage = [&](int buf, int k0) {
            GLDS16(BT + (size_t)(m0 + br0) * Kdim + k0 + c8,
                   Bs_ + buf * 128 * 32 + (w * 2 + 0) * 512);
            GLDS16(BT + (size_t)(m0 + br1) * Kdim + k0 + c8,
                   Bs_ + buf * 128 * 32 + (w * 2 + 1) * 512);
            const int ar = tid >> 1;
            const int kh = (tid & 1) * 16;
            const float* ap = (const float*)A + (size_t)(n0 + ar) * lda + k0 + kh;
            float4 v0 = ((const float4*)ap)[0];
            float4 v1 = ((const float4*)ap)[1];
            float4 v2 = ((const float4*)ap)[2];
            float4 v3 = ((const float4*)ap)[3];
            uint4 a0, a1;
            a0.x = (unsigned)f2b(v0.x) | ((unsigned)f2b(v0.y) << 16);
            a0.y = (unsigned)f2b(v0.z) | ((unsigned)f2b(v0.w) << 16);
            a0.z = (unsigned)f2b(v1.x) | ((unsigned)f2b(v1.y) << 16);
            a0.w = (unsigned)f2b(v1.z) | ((unsigned)f2b(v1.w) << 16);
            a1.x = (unsigned)f2b(v2.x) | ((unsigned)f2b(v2.y) << 16);
            a1.y = (unsigned)f2b(v2.z) | ((unsigned)f2b(v2.w) << 16);
            a1.z = (unsigned)f2b(v3.x) | ((unsigned)f2b(v3.y) << 16);
            a1.w = (unsigned)f2b(v3.z) | ((unsigned)f2b(v3.w) << 16);
            u16* arow = As_ + buf * BN * 32 + ar * 32;
            *(uint4*)&arow[swz(ar, kh)] = a0;
            *(uint4*)&arow[swz(ar, kh + 8)] = a1;
        };
        stage(0, 0);
        __syncthreads();
        int cur = 0;
        for (int t = 0; t < nsteps; ++t) {
            if (t + 1 < nsteps) stage(cur ^ 1, (t + 1) * 32);
            bfrag af[NT], bfv[4];
            #pragma unroll
            for (int it = 0; it < NT; it++)
                af[it] = *(const bfrag*)(As_ + cur * BN * 32
                         + (wi * (NT * 16) + it * 16 + lo16) * 32 + fcol);
            #pragma unroll
            for (int jt = 0; jt < 4; jt++)
                bfv[jt] = *(const bfrag*)(Bs_ + cur * 128 * 32
                          + (wj * 64 + jt * 16 + lo16) * 32 + fcol);
            __builtin_amdgcn_s_setprio(1);
            #pragma unroll
            for (int it = 0; it < NT; it++)
                #pragma unroll
                for (int jt = 0; jt < 4; jt++)
                    acc[it][jt] = __builtin_amdgcn_mfma_f32_16x16x32_bf16(
                        af[it], bfv[jt], acc[it][jt], 0, 0, 0);
            __builtin_amdgcn_s_setprio(0);
            if (t + 1 < nsteps) {
                __syncthreads();
                cur ^= 1;
            }
        }
    }
    // ---- epilogue ----
    #pragma unroll
    for (int jt = 0; jt < 4; jt++) {
        const int col = m0 + wj * 64 + jt * 16 + lo16;
        u16* Cp;
        int cc;
        if constexpr (SPLIT) {
            Cp = (col >> 10) ? C1 : C0;
            cc = col & 1023;
        } else {
            Cp = C0;
            cc = col;
        }
        const float bv = bias ? bias[bias_off + col] : 0.f;
        #pragma unroll
        for (int it = 0; it < NT; it++) {
            #pragma unroll
            for (int r = 0; r < 4; r++) {
                const int row = n0 + wi * (NT * 16) + it * 16 + quad * 4 + r;
                float v = acc[it][jt][r] + bv;
                if constexpr (RELU) v = fmaxf(v, 0.f);
                const int ccs = CSWZ ? swz(row, cc) : cc;
                u16* cp = Cp + (size_t)row * ldc + ccs;
                if constexpr (ACC) v += b2f_bits(*cp);
                *cp = f2b(v);
            }
        }
    }
}

// ---------------------------------------------------------------------------
// Old fp32-staging GEMM, kept only for the Q projection. XCD remap.
template <int AF32, int QKV, int RELU, int ACC>
__global__ __launch_bounds__(256) void mgemm(
    const void* __restrict__ A,
    const float* __restrict__ B0f, const float* __restrict__ B1f, const float* __restrict__ B2f,
    u16* __restrict__ C0, u16* __restrict__ C1, u16* __restrict__ C2,
    int ldb, int brow_off, int bcol_off,
    const float* __restrict__ bias, int bias_off)
{
    __shared__ alignas(16) u16 As[128][32];
    __shared__ alignas(16) u16 Bt[128][40];
    __shared__ alignas(16) float Bs32[32][132];

    const int tid = threadIdx.x;
    const int lane = tid & 63;
    const int w = tid >> 6;
    const int lo16 = lane & 15;
    const int quad = lane >> 4;
    const int wi = w >> 1, wj = w & 1;

    int bx, by;
    xcd_remap(gridDim.x, bx, by);
    const int m0 = bx * 128;
    const int n0 = by * 128;

    f32x4 acc[4][4] = {};

    const int ar  = tid >> 1;
    const int akh = (tid & 1) * 16;
    const int bmq = tid & 31;
    const int bkb = (tid >> 5) * 4;
    const int tm  = tid >> 1;
    const int tkh = (tid & 1) * 16;

    for (int k0 = 0; k0 < 1024; k0 += 32) {
        uint4 a0, a1;
        if constexpr (AF32) {
            const float* ap = (const float*)A + (size_t)(n0 + ar) * 1024 + k0 + akh;
            float4 v0 = ((const float4*)ap)[0];
            float4 v1 = ((const float4*)ap)[1];
            float4 v2 = ((const float4*)ap)[2];
            float4 v3 = ((const float4*)ap)[3];
            a0.x = (unsigned)f2b(v0.x) | ((unsigned)f2b(v0.y) << 16);
            a0.y = (unsigned)f2b(v0.z) | ((unsigned)f2b(v0.w) << 16);
            a0.z = (unsigned)f2b(v1.x) | ((unsigned)f2b(v1.y) << 16);
            a0.w = (unsigned)f2b(v1.z) | ((unsigned)f2b(v1.w) << 16);
            a1.x = (unsigned)f2b(v2.x) | ((unsigned)f2b(v2.y) << 16);
            a1.y = (unsigned)f2b(v2.z) | ((unsigned)f2b(v2.w) << 16);
            a1.z = (unsigned)f2b(v3.x) | ((unsigned)f2b(v3.y) << 16);
            a1.w = (unsigned)f2b(v3.z) | ((unsigned)f2b(v3.w) << 16);
        } else {
            const u16* ap = (const u16*)A + (size_t)(n0 + ar) * 1024 + k0 + akh;
            a0 = ((const uint4*)ap)[0];
            a1 = ((const uint4*)ap)[1];
        }
        #pragma unroll
        for (int kk = 0; kk < 4; kk++) {
            const int k = bkb + kk;
            const float* bp;
            if constexpr (QKV) {
                const int m = m0 + bmq * 4;
                const int sel = m >> 10;
                const int mm = m & 1023;
                const float* Wp = (sel == 0) ? B0f : ((sel == 1) ? B1f : B2f);
                bp = Wp + ((size_t)(mm >> 6) * 1024 + k0 + k) * 64 + (mm & 63);
            } else {
                bp = B0f + (size_t)(brow_off + k0 + k) * ldb + bcol_off + m0 + bmq * 4;
            }
            *(float4*)&Bs32[k][bmq * 4] = *(const float4*)bp;
        }
        __syncthreads();
        *(uint4*)&As[ar][akh] = a0;
        *(uint4*)&As[ar][akh + 8] = a1;
        {
            u16 t[16];
            #pragma unroll
            for (int i = 0; i < 16; i++) t[i] = f2b(Bs32[tkh + i][tm]);
            *(uint4*)&Bt[tm][tkh] = *(uint4*)&t[0];
            *(uint4*)&Bt[tm][tkh + 8] = *(uint4*)&t[8];
        }
        __syncthreads();
        bfrag af[4], bfv[4];
        #pragma unroll
        for (int it = 0; it < 4; it++)
            af[it] = *(const bfrag*)&As[wi * 64 + it * 16 + lo16][quad * 8];
        #pragma unroll
        for (int jt = 0; jt < 4; jt++)
            bfv[jt] = *(const bfrag*)&Bt[wj * 64 + jt * 16 + lo16][quad * 8];
        #pragma unroll
        for (int it = 0; it < 4; it++)
            #pragma unroll
            for (int jt = 0; jt < 4; jt++)
                acc[it][jt] = __builtin_amdgcn_mfma_f32_16x16x32_bf16(
                    af[it], bfv[jt], acc[it][jt], 0, 0, 0);
        __syncthreads();
    }
    #pragma unroll
    for (int jt = 0; jt < 4; jt++) {
        const int col = m0 + wj * 64 + jt * 16 + lo16;
        u16* Cp;
        int cc;
        if constexpr (QKV) {
            const int sel = col >> 10;
            cc = col & 1023;
            Cp = (sel == 0) ? C0 : ((sel == 1) ? C1 : C2);
        } else {
            Cp = C0;
            cc = col;
        }
        const float bv = bias ? bias[bias_off + col] : 0.f;
        #pragma unroll
        for (int it = 0; it < 4; it++) {
            #pragma unroll
            for (int r = 0; r < 4; r++) {
                const int row = n0 + wi * 64 + it * 16 + quad * 4 + r;
                float v = acc[it][jt][r] + bv;
                if constexpr (RELU) v = fmaxf(v, 0.f);
                u16* cp = Cp + (size_t)row * 1024 + cc;
                if constexpr (ACC) v += b2f_bits(*cp);
                *cp = f2b(v);
            }
        }
    }
}

// Flash attention (R13 body, best measured 86.2-86.8us): paired q-tiles
// (qp, 31-qp) processed SEQUENTIALLY, 512 blocks x 33 KV-tiles uniform.
// T14 reg prefetch per q-tile. No XCD swizzle. O written PRE-SWIZZLED.
__global__ __launch_bounds__(256) void fattn_kernel(
    u16* __restrict__ Q, const u16* __restrict__ Kg, const u16* __restrict__ Vg)
{
    const int bi = blockIdx.x;
    const int qp = bi & 15;
    const int h  = (bi >> 4) & 15;
    const int b  = bi >> 8;
    const int tid = threadIdx.x;
    const int w = tid >> 6;
    const int lane = tid & 63;
    const int lo16 = lane & 15;
    const int quad = lane >> 4;

    __shared__ alignas(16) u16 Ks[64][KP];
    __shared__ alignas(16) u16 Vt[64][KP];
    __shared__ alignas(16) u16 Ps[4][16][KP];

    const int sr = tid >> 2;
    const int ec = (tid & 3) * 16;

    #pragma unroll 1
    for (int pi = 0; pi < 2; pi++) {
        const int qt = pi ? (31 - qp) : qp;
        const int q0 = qt * 64;
        const size_t qrow = (size_t)(b * T_ + q0 + w * 16 + lo16) * 1024 + h * 64;
        bfrag qa0 = *(const bfrag*)(Q + qrow + quad * 8);
        bfrag qa1 = *(const bfrag*)(Q + qrow + 32 + quad * 8);

        f32x4 oacc[4] = {};
        float m_r[4], l_r[4];
        #pragma unroll
        for (int r = 0; r < 4; r++) { m_r[r] = -3e38f; l_r[r] = 0.f; }

        uint4 ka, kb, va, vb;
        {
            const size_t grow = (size_t)(b * T_ + sr) * 1024 + h * 64 + ec;
            ka = *(const uint4*)(Kg + grow);
            kb = *(const uint4*)(Kg + grow + 8);
            va = *(const uint4*)(Vg + grow);
            vb = *(const uint4*)(Vg + grow + 8);
        }

        for (int st = 0; st <= qt; st++) {
            *(uint4*)&Ks[sr][ec] = ka;
            *(uint4*)&Ks[sr][ec + 8] = kb;
            {
                unsigned vv[8] = {va.x, va.y, va.z, va.w, vb.x, vb.y, vb.z, vb.w};
                #pragma unroll
                for (int k2 = 0; k2 < 8; k2++) {
                    Vt[ec + 2 * k2][sr]     = (u16)(vv[k2] & 0xffff);
                    Vt[ec + 2 * k2 + 1][sr] = (u16)(vv[k2] >> 16);
                }
            }
            __syncthreads();
            if (st < qt) {
                const size_t grow = (size_t)(b * T_ + (st + 1) * 64 + sr) * 1024
                                  + h * 64 + ec;
                ka = *(const uint4*)(Kg + grow);
                kb = *(const uint4*)(Kg + grow + 8);
                va = *(const uint4*)(Vg + grow);
                vb = *(const uint4*)(Vg + grow + 8);
            }

            float sv[4][4];
            #pragma unroll
            for (int nt = 0; nt < 4; nt++) {
                bfrag kb0 = *(const bfrag*)&Ks[nt * 16 + lo16][quad * 8];
                bfrag kb1 = *(const bfrag*)&Ks[nt * 16 + lo16][32 + quad * 8];
                f32x4 cs = {0.f, 0.f, 0.f, 0.f};
                cs = __builtin_amdgcn_mfma_f32_16x16x32_bf16(qa0, kb0, cs, 0, 0, 0);
                cs = __builtin_amdgcn_mfma_f32_16x16x32_bf16(qa1, kb1, cs, 0, 0, 0);
                #pragma unroll
                for (int r = 0; r < 4; r++) sv[nt][r] = cs[r] * 0.125f;
            }
            if (st == qt) {
                #pragma unroll
                for (int nt = 0; nt < 4; nt++)
                    #pragma unroll
                    for (int r = 0; r < 4; r++)
                        if (nt * 16 + lo16 > w * 16 + quad * 4 + r) sv[nt][r] = -3e38f;
            }
            #pragma unroll
            for (int r = 0; r < 4; r++) {
                float m = fmaxf(fmaxf(sv[0][r], sv[1][r]), fmaxf(sv[2][r], sv[3][r]));
                #pragma unroll
                for (int off = 1; off < 16; off <<= 1)
                    m = fmaxf(m, __shfl_xor(m, off, 64));
                float mnew = fmaxf(m_r[r], m);
                float alpha = __expf(m_r[r] - mnew);
                m_r[r] = mnew;
                float s = 0.f;
                #pragma unroll
                for (int nt = 0; nt < 4; nt++) {
                    sv[nt][r] = __expf(sv[nt][r] - mnew);
                    s += sv[nt][r];
                }
                #pragma unroll
                for (int off = 1; off < 16; off <<= 1)
                    s += __shfl_xor(s, off, 64);
                l_r[r] = l_r[r] * alpha + s;
                #pragma unroll
                for (int et = 0; et < 4; et++) oacc[et][r] *= alpha;
            }
            #pragma unroll
            for (int nt = 0; nt < 4; nt++)
                #pragma unroll
                for (int r = 0; r < 4; r++)
                    Ps[w][quad * 4 + r][nt * 16 + lo16] = f2b(sv[nt][r]);
            bfrag pa0 = *(const bfrag*)&Ps[w][lo16][quad * 8];
            bfrag pa1 = *(const bfrag*)&Ps[w][lo16][32 + quad * 8];
            #pragma unroll
            for (int et = 0; et < 4; et++) {
                bfrag vb0 = *(const bfrag*)&Vt[et * 16 + lo16][quad * 8];
                bfrag vb1 = *(const bfrag*)&Vt[et * 16 + lo16][32 + quad * 8];
                oacc[et] = __builtin_amdgcn_mfma_f32_16x16x32_bf16(pa0, vb0, oacc[et], 0, 0, 0);
                oacc[et] = __builtin_amdgcn_mfma_f32_16x16x32_bf16(pa1, vb1, oacc[et], 0, 0, 0);
            }
            __syncthreads();
        }
        #pragma unroll
        for (int r = 0; r < 4; r++) {
            float rl = 1.f / l_r[r];
            const int row = q0 + w * 16 + quad * 4 + r;
            u16* orow = Q + (size_t)(b * T_ + row) * 1024;
            #pragma unroll
            for (int et = 0; et < 4; et++)
                orow[swz(row, h * 64 + et * 16 + lo16)] = f2b(oacc[et][r] * rl);
        }
    }
}

// LN(src bf16)*g + be + resid(fp32). WF32=1 -> fp32 dstf, else bf16 dstb
// (OSWZ: bf16 output written pre-swizzled for cgemm A consumption).
template <int WF32, int OSWZ>
__global__ __launch_bounds__(256) void ln_kernel(
    const u16* __restrict__ src, const float* __restrict__ resid,
    const float* __restrict__ g, const float* __restrict__ be,
    u16* __restrict__ dstb, float* __restrict__ dstf)
{
    const int r = blockIdx.x;
    const int tid = threadIdx.x;
    uint2 raw = ((const uint2*)(src + (size_t)r * D_))[tid];
    float y[4];
    y[0] = __uint_as_float(raw.x << 16);
    y[1] = __uint_as_float(raw.x & 0xffff0000u);
    y[2] = __uint_as_float(raw.y << 16);
    y[3] = __uint_as_float(raw.y & 0xffff0000u);
    float s = y[0] + y[1] + y[2] + y[3];
    float sq = y[0]*y[0] + y[1]*y[1] + y[2]*y[2] + y[3]*y[3];
    #pragma unroll
    for (int o = 32; o > 0; o >>= 1) {
        s += __shfl_down(s, o, 64);
        sq += __shfl_down(sq, o, 64);
    }
    __shared__ float rs[4], rq[4];
    if ((tid & 63) == 0) { rs[tid >> 6] = s; rq[tid >> 6] = sq; }
    __syncthreads();
    const float S = rs[0] + rs[1] + rs[2] + rs[3];
    const float Qm = rq[0] + rq[1] + rq[2] + rq[3];
    const float mu = S * (1.f / (float)D_);
    const float var = fmaxf(Qm * (1.f / (float)D_) - mu * mu, 0.f);
    const float rstd = rsqrtf(var + EPS_);
    const int c = tid * 4;
    #pragma unroll
    for (int i = 0; i < 4; i++) {
        y[i] = (y[i] - mu) * rstd * g[c + i] + be[c + i]
             + resid[(size_t)r * D_ + c + i];
    }
    if constexpr (WF32) {
        float4 o = {y[0], y[1], y[2], y[3]};
        ((float4*)(dstf + (size_t)r * D_))[tid] = o;
    } else {
        uint2 o;
        o.x = (unsigned)f2b(y[0]) | ((unsigned)f2b(y[1]) << 16);
        o.y = (unsigned)f2b(y[2]) | ((unsigned)f2b(y[3]) << 16);
        const int cs = OSWZ ? swz(r, c) : c;
        *(uint2*)(dstb + (size_t)r * D_ + cs) = o;
    }
}

extern "C" void kernel_launch(void* const* d_in, const int* in_sizes, int n_in,
                              void* d_out, int out_size, void* d_ws, size_t ws_size,
                              hipStream_t stream)
{
    const float* emb = (const float*)d_in[0];
    const float* Wq  = (const float*)d_in[1];
    const float* Wk  = (const float*)d_in[2];
    const float* Wv  = (const float*)d_in[3];
    const float* Wo  = (const float*)d_in[4];
    const float* bo  = (const float*)d_in[5];
    const float* W1  = (const float*)d_in[6];
    const float* b1  = (const float*)d_in[7];
    const float* W2  = (const float*)d_in[8];
    const float* b2  = (const float*)d_in[9];
    const float* g1  = (const float*)d_in[10];
    const float* be1 = (const float*)d_in[11];
    const float* g2  = (const float*)d_in[12];
    const float* be2 = (const float*)d_in[13];

    u16* WS = (u16*)d_ws;       // 4M u16
    u16* DO = (u16*)d_out;      // 8M u16

    const size_t M1 = 1024 * 1024;
    u16* WkvT = WS;                      // [2048][1024] bf16 swz (4MB)
    u16* Q    = WS;                      // natural (over dead WkvT)
    u16* Kb   = DO;                      // [0,4M) natural
    u16* Vb   = DO + 4 * M1;             // [4M,8M) natural
    u16* O    = WS;                      // fattn writes O (swz) over Q
    u16* WoT  = DO;                      // [0,1M) swz, over dead K
    u16* P    = DO + 4 * M1;             // [4M,8M) natural, over dead V
    u16* Af   = DO;                      // [0,4M) swz, over dead WoT
    u16* Hc   = DO + 4 * M1;             // [4M,6M) [2048][1024] swz
    u16* W1T  = DO + 6 * M1;             // [6M,7M) swz
    u16* W2T  = DO + 7 * M1;             // [7M,8M) swz
    u16* F    = WS;                      // natural, over dead O
    float* outf = (float*)d_out;

    const dim3 blk(256);

    // 1) Wk,Wv -> WkvT bf16 swz (one launch)
    tcvt_kv<<<dim3(1, 16, 32), blk, 0, stream>>>(Wk, Wv, WkvT);
    // 2) K,V = emb @ WkvT^T  (A fp32, split output, natural C; 2-phase)
    cgemm<1, 1, 0, 0, 4, 0, 0><<<dim3(16, 32), blk, 0, stream>>>(
        emb, 1024, WkvT, Kb, Vb, 1024, 1024, nullptr, 0);
    // 3) Q = emb @ Wq (old fp32-staging path, natural)
    mgemm<1, 1, 0, 0><<<dim3(8, 32), blk, 0, stream>>>(
        emb, Wq, Wq, Wq, Q, nullptr, nullptr, 0, 0, 0, nullptr, 0);
    // 4) flash attention (R13 body), O (swz) over Q
    fattn_kernel<<<Bq_ * H_ * 16, blk, 0, stream>>>(Q, Kb, Vb);
    // 5) Wo -> WoT bf16 swz (over dead K)
    tcvt<<<dim3(16, 16), blk, 0, stream>>>(Wo, 1024, 0, 0, WoT, 1024, 0);
    // 6) P = O @ WoT^T + bo (natural C, over dead V; WAVE NT=4)
    cgemm<0, 0, 0, 0, 4, 0, 1><<<dim3(8, 32), blk, 0, stream>>>(
        O, 1024, WoT, P, nullptr, 1024, 1024, bo, 0);
    // 7) Af = LN(P) + emb (swz out)
    ln_kernel<0, 1><<<N_, blk, 0, stream>>>(P, emb, g1, be1, Af, nullptr);
    // 8) FFN: 4 hidden chunks x 2 row-halves; NT=2 WAVE, 256-block grids
    for (int c = 0; c < 4; c++) {
        tcvt_ffn<<<dim3(16, 16, 2), blk, 0, stream>>>(W1, W2, c, W1T, W2T);
        for (int rh = 0; rh < 2; rh++) {
            u16* Afh = Af + (size_t)rh * 2048 * 1024;
            u16* Fh  = F  + (size_t)rh * 2048 * 1024;
            cgemm<0, 0, 1, 0, 2, 1, 1><<<dim3(8, 32), blk, 0, stream>>>(
                Afh, 1024, W1T, Hc, nullptr, 1024, 1024, b1, c * 1024);
            if (c == 0) {
                cgemm<0, 0, 0, 0, 2, 0, 1><<<dim3(8, 32), blk, 0, stream>>>(
                    Hc, 1024, W2T, Fh, nullptr, 1024, 1024, b2, 0);
            } else {
                cgemm<0, 0, 0, 1, 2, 0, 1><<<dim3(8, 32), blk, 0, stream>>>(
                    Hc, 1024, W2T, Fh, nullptr, 1024, 1024, nullptr, 0);
            }
        }
    }
    // 9) out = fp32(LN(F) + emb)
    ln_kernel<1, 0><<<N_, blk, 0, stream>>>(F, emb, g2, be2, nullptr, outf);
}

// Round 9
// 535.437 us; speedup vs baseline: 1.1650x; 1.0235x over previous
//
#include <hip/hip_runtime.h>
#include <hip/hip_bf16.h>

// Transformer block, B=2 T=2048 D=1024 H=16 DH=64 F=4096. fp32 in/out.
// R18 = R17 + V stored PRE-TRANSPOSED by the KV gemm epilogue:
//  - cgemm<SPLIT,VT=1>: V half written as V^T[b][h][dh][t] (uint2-packed,
//    4 consecutive t per write). fattn stages V^T rows with the same
//    conflict-free uint4 pattern as K — kills the per-tile 16-scalar-u16
//    LDS transpose that caused 11.35M SQ_LDS_BANK_CONFLICT (~25% of
//    fattn time). Bit-identical values, layout-only change.
//  - Everything else exactly R17 (best measured: 548us, fattn 86,
//    GEMMs R15 config). Numerics verified absmax 0.046875.

#define Bq_ 2
#define T_ 2048
#define D_ 1024
#define H_ 16
#define DH_ 64
#define F_ 4096
#define N_ (Bq_ * T_)   // 4096 rows
#define EPS_ 1e-5f
#define KP 72           // flash-attn LDS pitch

typedef __hip_bfloat16 bf16;
typedef unsigned short u16;
typedef __attribute__((ext_vector_type(8))) short bfrag;   // 8 bf16 = 4 VGPRs
typedef __attribute__((ext_vector_type(4))) float f32x4;

__device__ __forceinline__ u16 f2b(float f) {
    bf16 h = __float2bfloat16(f);
    return *(u16*)&h;
}
__device__ __forceinline__ float b2f_bits(u16 u) {
    return __uint_as_float(((unsigned)u) << 16);
}

// T2 swizzle: permute 16B (8xu16) blocks within each 32-u16 K-window by
// XOR with (row>>1)&3. Involution; preserves col&7 and col&~31.
__device__ __forceinline__ int swz(int row, int col) {
    return (col & ~31) | ((((col >> 3) ^ (row >> 1)) & 3) << 3) | (col & 7);
}

template <int N>
__device__ __forceinline__ void vmwait() {
    asm volatile("s_waitcnt vmcnt(%0)" :: "i"(N) : "memory");
}

#define GLDS16(g, l) __builtin_amdgcn_global_load_lds( \
    (const __attribute__((address_space(1))) unsigned int*)(g), \
    (__attribute__((address_space(3))) unsigned int*)(l), 16, 0, 0)

// XCD-aware block remap: blocks sharing an A-panel (same y, all gx x's)
// get linear ids ≡ same value (mod 8) -> dispatched to the same XCD.
// Requires gy % 8 == 0.
__device__ __forceinline__ void xcd_remap(int gx, int& bx, int& by) {
    const int bid = blockIdx.x + gx * blockIdx.y;
    const int t8 = bid >> 3;
    bx = t8 % gx;
    by = (bid & 7) + 8 * (t8 / gx);
}

// ---------------------------------------------------------------------------
// 64x64 fp32 transpose+cvt tile body -> bf16 dst rows drow0..+63 (swz'd).
__device__ __forceinline__ void tc_body(
    float (*Ts)[65], const float* s, int spitch,
    u16* dst, int dpitch, int drow0, int kcol0)
{
    const int t = threadIdx.x;
    #pragma unroll
    for (int i = 0; i < 4; i++) {
        const int idx = t + i * 256;
        const int kk = idx >> 4;
        const int mm = (idx & 15) * 4;
        float4 v = *(const float4*)(s + (size_t)kk * spitch + mm);
        Ts[mm][kk] = v.x; Ts[mm + 1][kk] = v.y;
        Ts[mm + 2][kk] = v.z; Ts[mm + 3][kk] = v.w;
    }
    __syncthreads();
    const int mm = t >> 2;
    const int kk0 = (t & 3) * 16;
    u16 o[16];
    #pragma unroll
    for (int j = 0; j < 16; j++) o[j] = f2b(Ts[mm][kk0 + j]);
    const int dr = drow0 + mm;
    u16* drow = dst + (size_t)dr * dpitch;
    const int c0 = kcol0 + kk0;
    *(uint4*)&drow[swz(dr, c0)]     = *(uint4*)&o[0];
    *(uint4*)&drow[swz(dr, c0 + 8)] = *(uint4*)&o[8];
}

// Generic tcvt (used for Wo): fp32 [K,M] slice -> bf16 [M,K] swz.
__global__ __launch_bounds__(256) void tcvt(
    const float* __restrict__ src, int spitch, int srow0, int scol0,
    u16* __restrict__ dst, int dpitch, int drow0)
{
    __shared__ float Ts[64][65];
    const int mb = blockIdx.x, kb = blockIdx.y;
    const float* s = src + (size_t)(srow0 + kb * 64) * spitch + scol0 + mb * 64;
    tc_body(Ts, s, spitch, dst, dpitch, drow0 + mb * 64, kb * 64);
}

// Fused Wk+Wv -> WkvT [2048][1024] swz. grid (1,16,32).
__global__ __launch_bounds__(256) void tcvt_kv(
    const float* __restrict__ Wk, const float* __restrict__ Wv,
    u16* __restrict__ dst)
{
    __shared__ float Ts[64][65];
    const int kb = blockIdx.y, z = blockIdx.z;
    const int sel = z >> 4, zz = z & 15;
    const float* src = sel ? Wv : Wk;
    const float* s = src + (size_t)zz * 1024 * 64 + (size_t)(kb * 64) * 64;
    tc_body(Ts, s, 64, dst, 1024, sel * 1024 + zz * 64, kb * 64);
}

// Fused FFN chunk transpose: z=0 -> W1 cols; z=1 -> W2 rows. grid (16,16,2).
__global__ __launch_bounds__(256) void tcvt_ffn(
    const float* __restrict__ W1, const float* __restrict__ W2, int c,
    u16* __restrict__ W1T, u16* __restrict__ W2T)
{
    __shared__ float Ts[64][65];
    const int mb = blockIdx.x, kb = blockIdx.y, z = blockIdx.z;
    const float* src = z ? W2 : W1;
    const int spitch = z ? 1024 : 4096;
    const int srow0  = z ? c * 1024 : 0;
    const int scol0  = z ? 0 : c * 1024;
    u16* dst = z ? W2T : W1T;
    const float* s = src + (size_t)(srow0 + kb * 64) * spitch + scol0 + mb * 64;
    tc_body(Ts, s, spitch, dst, 1024, mb * 64, kb * 64);
}

// ---------------------------------------------------------------------------
// cgemm: C[N, M] = A[N, lda] @ BT[M, Kdim]^T (+bias)(+relu)(+ACC), bf16 out.
// A: AF32 ? fp32 natural (cvt in reg; 2-phase barrier path)
//         : bf16 PRE-SWIZZLED (global_load_lds).
// BT: bf16 PRE-SWIZZLED, pitch=Kdim. Fragment reads XOR-swizzled.
// WAVE (requires !AF32): barrier-free wave-autonomous pipeline.
// VT (requires SPLIT): col>=1024 half written TRANSPOSED to C1 as
// V^T[b][h][dh][t] = C1[(b*1024 + (col&1023))*2048 + t], uint2-packed.
template <int AF32, int SPLIT, int RELU, int ACC, int NT, int CSWZ, int WAVE, int VT>
__global__ __launch_bounds__(256) void cgemm(
    const void* __restrict__ A, int lda,
    const u16* __restrict__ BT,
    u16* __restrict__ C0, u16* __restrict__ C1, int ldc,
    int Kdim,
    const float* __restrict__ bias, int bias_off)
{
    static_assert(NT == 2 || NT == 4, "NT");
    static_assert(!AF32 || NT == 4, "AF32 path assumes BN=128");
    static_assert(!(AF32 && WAVE), "WAVE requires glds-only staging");
    static_assert(!VT || SPLIT, "VT requires SPLIT");
    constexpr int BN = NT * 32;
    constexpr int NBUF = (NT == 2) ? 5 : 4;   // wave-private buffers
    constexpr int DPT  = NBUF - 1;            // pipeline depth
    constexpr int LPT  = 4 + NT;              // glds per wave per tile
    constexpr int BELEM = 64 * 32;            // u16 per B slice
    constexpr int AELEM = NT * 16 * 32;       // u16 per A slice
    constexpr int PBUF  = BELEM + AELEM;
    constexpr int SELEM = WAVE ? 4 * NBUF * PBUF
                               : 2 * BN * 32 + 2 * 128 * 32;
    __shared__ alignas(16) u16 SMEM[SELEM];

    const int tid = threadIdx.x;
    const int lane = tid & 63;
    const int w = tid >> 6;
    const int lo16 = lane & 15;
    const int quad = lane >> 4;
    const int wi = w >> 1, wj = w & 1;

    int bx, by;
    xcd_remap(gridDim.x, bx, by);
    const int m0 = bx * 128;
    const int n0 = by * BN;

    f32x4 acc[NT][4] = {};

    const int c8 = (lane & 3) * 8;          // elem offset within row
    const int r4 = lane >> 2;               // row within a 16-row call
    // swizzled fragment column (row s-bits reduce to lane-only)
    const int fcol = ((quad ^ ((lo16 >> 1) & 3)) << 3);

    const int nsteps = Kdim >> 5;

    if constexpr (WAVE) {
        const u16* Ab = (const u16*)A;
        u16* wbase = &SMEM[w * NBUF * PBUF];
        auto wstage = [&](int slot, int k0) {
            u16* bb = wbase + slot * PBUF;
            #pragma unroll
            for (int c = 0; c < 4; c++)
                GLDS16(BT + (size_t)(m0 + wj * 64 + c * 16 + r4) * Kdim + k0 + c8,
                       bb + c * 512);
            u16* ab = bb + BELEM;
            #pragma unroll
            for (int c = 0; c < NT; c++)
                GLDS16(Ab + (size_t)(n0 + wi * (NT * 16) + c * 16 + r4) * lda + k0 + c8,
                       ab + c * 512);
        };
        #pragma unroll
        for (int i = 0; i < DPT; i++) wstage(i, i * 32);
        int t = 0, cb = 0;
        for (; t + DPT <= nsteps; ++t) {
            vmwait<(DPT - 1) * LPT>();
            __builtin_amdgcn_sched_barrier(0);
            const u16* bb = wbase + cb * PBUF;
            const u16* ab = bb + BELEM;
            bfrag af[NT], bfv[4];
            #pragma unroll
            for (int it = 0; it < NT; it++)
                af[it] = *(const bfrag*)(ab + (it * 16 + lo16) * 32 + fcol);
            #pragma unroll
            for (int jt = 0; jt < 4; jt++)
                bfv[jt] = *(const bfrag*)(bb + (jt * 16 + lo16) * 32 + fcol);
            if (t + DPT < nsteps)
                wstage(cb == 0 ? NBUF - 1 : cb - 1, (t + DPT) * 32);
            __builtin_amdgcn_s_setprio(1);
            #pragma unroll
            for (int it = 0; it < NT; it++)
                #pragma unroll
                for (int jt = 0; jt < 4; jt++)
                    acc[it][jt] = __builtin_amdgcn_mfma_f32_16x16x32_bf16(
                        af[it], bfv[jt], acc[it][jt], 0, 0, 0);
            __builtin_amdgcn_s_setprio(0);
            cb = (cb + 1 == NBUF) ? 0 : cb + 1;
        }
        vmwait<0>();
        __builtin_amdgcn_sched_barrier(0);
        for (; t < nsteps; ++t) {
            const u16* bb = wbase + cb * PBUF;
            const u16* ab = bb + BELEM;
            bfrag af[NT], bfv[4];
            #pragma unroll
            for (int it = 0; it < NT; it++)
                af[it] = *(const bfrag*)(ab + (it * 16 + lo16) * 32 + fcol);
            #pragma unroll
            for (int jt = 0; jt < 4; jt++)
                bfv[jt] = *(const bfrag*)(bb + (jt * 16 + lo16) * 32 + fcol);
            #pragma unroll
            for (int it = 0; it < NT; it++)
                #pragma unroll
                for (int jt = 0; jt < 4; jt++)
                    acc[it][jt] = __builtin_amdgcn_mfma_f32_16x16x32_bf16(
                        af[it], bfv[jt], acc[it][jt], 0, 0, 0);
            cb = (cb + 1 == NBUF) ? 0 : cb + 1;
        }
    } else {
        // 2-phase barrier path (AF32 only): shared As/Bs tiles.
        u16* As_ = SMEM;                    // [2][BN][32]
        u16* Bs_ = SMEM + 2 * BN * 32;      // [2][128][32]
        const int br0 = w * 32 + r4;
        const int br1 = br0 + 16;
        auto stage = [&](int buf, int k0) {
            GLDS16(BT + (size_t)(m0 + br0) * Kdim + k0 + c8,
                   Bs_ + buf * 128 * 32 + (w * 2 + 0) * 512);
            GLDS16(BT + (size_t)(m0 + br1) * Kdim + k0 + c8,
                   Bs_ + buf * 128 * 32 + (w * 2 + 1) * 512);
            const int ar = tid >> 1;
            const int kh = (tid & 1) * 16;
            const float* ap = (const float*)A + (size_t)(n0 + ar) * lda + k0 + kh;
            float4 v0 = ((const float4*)ap)[0];
            float4 v1 = ((const float4*)ap)[1];
            float4 v2 = ((const float4*)ap)[2];
            float4 v3 = ((const float4*)ap)[3];
            uint4 a0, a1;
            a0.x = (unsigned)f2b(v0.x) | ((unsigned)f2b(v0.y) << 16);
            a0.y = (unsigned)f2b(v0.z) | ((unsigned)f2b(v0.w) << 16);
            a0.z = (unsigned)f2b(v1.x) | ((unsigned)f2b(v1.y) << 16);
            a0.w = (unsigned)f2b(v1.z) | ((unsigned)f2b(v1.w) << 16);
            a1.x = (unsigned)f2b(v2.x) | ((unsigned)f2b(v2.y) << 16);
            a1.y = (unsigned)f2b(v2.z) | ((unsigned)f2b(v2.w) << 16);
            a1.z = (unsigned)f2b(v3.x) | ((unsigned)f2b(v3.y) << 16);
            a1.w = (unsigned)f2b(v3.z) | ((unsigned)f2b(v3.w) << 16);
            u16* arow = As_ + buf * BN * 32 + ar * 32;
            *(uint4*)&arow[swz(ar, kh)] = a0;
            *(uint4*)&arow[swz(ar, kh + 8)] = a1;
        };
        stage(0, 0);
        __syncthreads();
        int cur = 0;
        for (int t = 0; t < nsteps; ++t) {
            if (t + 1 < nsteps) stage(cur ^ 1, (t + 1) * 32);
            bfrag af[NT], bfv[4];
            #pragma unroll
            for (int it = 0; it < NT; it++)
                af[it] = *(const bfrag*)(As_ + cur * BN * 32
                         + (wi * (NT * 16) + it * 16 + lo16) * 32 + fcol);
            #pragma unroll
            for (int jt = 0; jt < 4; jt++)
                bfv[jt] = *(const bfrag*)(Bs_ + cur * 128 * 32
                          + (wj * 64 + jt * 16 + lo16) * 32 + fcol);
            __builtin_amdgcn_s_setprio(1);
            #pragma unroll
            for (int it = 0; it < NT; it++)
                #pragma unroll
                for (int jt = 0; jt < 4; jt++)
                    acc[it][jt] = __builtin_amdgcn_mfma_f32_16x16x32_bf16(
                        af[it], bfv[jt], acc[it][jt], 0, 0, 0);
            __builtin_amdgcn_s_setprio(0);
            if (t + 1 < nsteps) {
                __syncthreads();
                cur ^= 1;
            }
        }
    }
    // ---- epilogue ----
    #pragma unroll
    for (int jt = 0; jt < 4; jt++) {
        const int col = m0 + wj * 64 + jt * 16 + lo16;
        const bool vhalf = SPLIT && (col >> 10);
        const int cc = SPLIT ? (col & 1023) : col;
        if (VT && vhalf) {
            // V^T packed write: 4 consecutive t per uint2.
            #pragma unroll
            for (int it = 0; it < NT; it++) {
                const int rowb = n0 + wi * (NT * 16) + it * 16 + quad * 4;
                u16 pk[4];
                #pragma unroll
                for (int r = 0; r < 4; r++) pk[r] = f2b(acc[it][jt][r]);
                *(uint2*)(C1 + ((size_t)((rowb >> 11) * 1024 + cc)) * 2048
                          + (rowb & 2047)) = *(uint2*)pk;
            }
        } else {
            u16* Cp = vhalf ? C1 : C0;
            const float bv = bias ? bias[bias_off + col] : 0.f;
            #pragma unroll
            for (int it = 0; it < NT; it++) {
                #pragma unroll
                for (int r = 0; r < 4; r++) {
                    const int row = n0 + wi * (NT * 16) + it * 16 + quad * 4 + r;
                    float v = acc[it][jt][r] + bv;
                    if constexpr (RELU) v = fmaxf(v, 0.f);
                    const int ccs = CSWZ ? swz(row, cc) : cc;
                    u16* cp = Cp + (size_t)row * ldc + ccs;
                    if constexpr (ACC) v += b2f_bits(*cp);
                    *cp = f2b(v);
                }
            }
        }
    }
}

// ---------------------------------------------------------------------------
// Old fp32-staging GEMM, kept only for the Q projection. XCD remap.
template <int AF32, int QKV, int RELU, int ACC>
__global__ __launch_bounds__(256) void mgemm(
    const void* __restrict__ A,
    const float* __restrict__ B0f, const float* __restrict__ B1f, const float* __restrict__ B2f,
    u16* __restrict__ C0, u16* __restrict__ C1, u16* __restrict__ C2,
    int ldb, int brow_off, int bcol_off,
    const float* __restrict__ bias, int bias_off)
{
    __shared__ alignas(16) u16 As[128][32];
    __shared__ alignas(16) u16 Bt[128][40];
    __shared__ alignas(16) float Bs32[32][132];

    const int tid = threadIdx.x;
    const int lane = tid & 63;
    const int w = tid >> 6;
    const int lo16 = lane & 15;
    const int quad = lane >> 4;
    const int wi = w >> 1, wj = w & 1;

    int bx, by;
    xcd_remap(gridDim.x, bx, by);
    const int m0 = bx * 128;
    const int n0 = by * 128;

    f32x4 acc[4][4] = {};

    const int ar  = tid >> 1;
    const int akh = (tid & 1) * 16;
    const int bmq = tid & 31;
    const int bkb = (tid >> 5) * 4;
    const int tm  = tid >> 1;
    const int tkh = (tid & 1) * 16;

    for (int k0 = 0; k0 < 1024; k0 += 32) {
        uint4 a0, a1;
        if constexpr (AF32) {
            const float* ap = (const float*)A + (size_t)(n0 + ar) * 1024 + k0 + akh;
            float4 v0 = ((const float4*)ap)[0];
            float4 v1 = ((const float4*)ap)[1];
            float4 v2 = ((const float4*)ap)[2];
            float4 v3 = ((const float4*)ap)[3];
            a0.x = (unsigned)f2b(v0.x) | ((unsigned)f2b(v0.y) << 16);
            a0.y = (unsigned)f2b(v0.z) | ((unsigned)f2b(v0.w) << 16);
            a0.z = (unsigned)f2b(v1.x) | ((unsigned)f2b(v1.y) << 16);
            a0.w = (unsigned)f2b(v1.z) | ((unsigned)f2b(v1.w) << 16);
            a1.x = (unsigned)f2b(v2.x) | ((unsigned)f2b(v2.y) << 16);
            a1.y = (unsigned)f2b(v2.z) | ((unsigned)f2b(v2.w) << 16);
            a1.z = (unsigned)f2b(v3.x) | ((unsigned)f2b(v3.y) << 16);
            a1.w = (unsigned)f2b(v3.z) | ((unsigned)f2b(v3.w) << 16);
        } else {
            const u16* ap = (const u16*)A + (size_t)(n0 + ar) * 1024 + k0 + akh;
            a0 = ((const uint4*)ap)[0];
            a1 = ((const uint4*)ap)[1];
        }
        #pragma unroll
        for (int kk = 0; kk < 4; kk++) {
            const int k = bkb + kk;
            const float* bp;
            if constexpr (QKV) {
                const int m = m0 + bmq * 4;
                const int sel = m >> 10;
                const int mm = m & 1023;
                const float* Wp = (sel == 0) ? B0f : ((sel == 1) ? B1f : B2f);
                bp = Wp + ((size_t)(mm >> 6) * 1024 + k0 + k) * 64 + (mm & 63);
            } else {
                bp = B0f + (size_t)(brow_off + k0 + k) * ldb + bcol_off + m0 + bmq * 4;
            }
            *(float4*)&Bs32[k][bmq * 4] = *(const float4*)bp;
        }
        __syncthreads();
        *(uint4*)&As[ar][akh] = a0;
        *(uint4*)&As[ar][akh + 8] = a1;
        {
            u16 t[16];
            #pragma unroll
            for (int i = 0; i < 16; i++) t[i] = f2b(Bs32[tkh + i][tm]);
            *(uint4*)&Bt[tm][tkh] = *(uint4*)&t[0];
            *(uint4*)&Bt[tm][tkh + 8] = *(uint4*)&t[8];
        }
        __syncthreads();
        bfrag af[4], bfv[4];
        #pragma unroll
        for (int it = 0; it < 4; it++)
            af[it] = *(const bfrag*)&As[wi * 64 + it * 16 + lo16][quad * 8];
        #pragma unroll
        for (int jt = 0; jt < 4; jt++)
            bfv[jt] = *(const bfrag*)&Bt[wj * 64 + jt * 16 + lo16][quad * 8];
        #pragma unroll
        for (int it = 0; it < 4; it++)
            #pragma unroll
            for (int jt = 0; jt < 4; jt++)
                acc[it][jt] = __builtin_amdgcn_mfma_f32_16x16x32_bf16(
                    af[it], bfv[jt], acc[it][jt], 0, 0, 0);
        __syncthreads();
    }
    #pragma unroll
    for (int jt = 0; jt < 4; jt++) {
        const int col = m0 + wj * 64 + jt * 16 + lo16;
        u16* Cp;
        int cc;
        if constexpr (QKV) {
            const int sel = col >> 10;
            cc = col & 1023;
            Cp = (sel == 0) ? C0 : ((sel == 1) ? C1 : C2);
        } else {
            Cp = C0;
            cc = col;
        }
        const float bv = bias ? bias[bias_off + col] : 0.f;
        #pragma unroll
        for (int it = 0; it < 4; it++) {
            #pragma unroll
            for (int r = 0; r < 4; r++) {
                const int row = n0 + wi * 64 + it * 16 + quad * 4 + r;
                float v = acc[it][jt][r] + bv;
                if constexpr (RELU) v = fmaxf(v, 0.f);
                u16* cp = Cp + (size_t)row * 1024 + cc;
                if constexpr (ACC) v += b2f_bits(*cp);
                *cp = f2b(v);
            }
        }
    }
}

// Flash attention (R13 body + V^T staging): paired q-tiles (qp, 31-qp)
// SEQUENTIAL, 512 blocks. V read from pre-transposed Vt_g[b][h][dh][t] —
// row-major uint4 staging, no in-kernel transpose. O written PRE-SWIZZLED.
__global__ __launch_bounds__(256) void fattn_kernel(
    u16* __restrict__ Q, const u16* __restrict__ Kg, const u16* __restrict__ Vg)
{
    const int bi = blockIdx.x;
    const int qp = bi & 15;
    const int h  = (bi >> 4) & 15;
    const int b  = bi >> 8;
    const int tid = threadIdx.x;
    const int w = tid >> 6;
    const int lane = tid & 63;
    const int lo16 = lane & 15;
    const int quad = lane >> 4;

    __shared__ alignas(16) u16 Ks[64][KP];
    __shared__ alignas(16) u16 Vt[64][KP];
    __shared__ alignas(16) u16 Ps[4][16][KP];

    const int sr = tid >> 2;
    const int ec = (tid & 3) * 16;
    // V^T row base for this thread: Vg[(b*1024 + h*64 + sr)*2048 + t]
    const size_t vrow = ((size_t)(b * 1024 + h * 64 + sr)) * 2048;

    #pragma unroll 1
    for (int pi = 0; pi < 2; pi++) {
        const int qt = pi ? (31 - qp) : qp;
        const int q0 = qt * 64;
        const size_t qrow = (size_t)(b * T_ + q0 + w * 16 + lo16) * 1024 + h * 64;
        bfrag qa0 = *(const bfrag*)(Q + qrow + quad * 8);
        bfrag qa1 = *(const bfrag*)(Q + qrow + 32 + quad * 8);

        f32x4 oacc[4] = {};
        float m_r[4], l_r[4];
        #pragma unroll
        for (int r = 0; r < 4; r++) { m_r[r] = -3e38f; l_r[r] = 0.f; }

        uint4 ka, kb, va, vb;
        {
            const size_t grow = (size_t)(b * T_ + sr) * 1024 + h * 64 + ec;
            ka = *(const uint4*)(Kg + grow);
            kb = *(const uint4*)(Kg + grow + 8);
            va = *(const uint4*)(Vg + vrow + ec);
            vb = *(const uint4*)(Vg + vrow + ec + 8);
        }

        for (int st = 0; st <= qt; st++) {
            *(uint4*)&Ks[sr][ec] = ka;
            *(uint4*)&Ks[sr][ec + 8] = kb;
            *(uint4*)&Vt[sr][ec] = va;
            *(uint4*)&Vt[sr][ec + 8] = vb;
            __syncthreads();
            if (st < qt) {
                const size_t grow = (size_t)(b * T_ + (st + 1) * 64 + sr) * 1024
                                  + h * 64 + ec;
                ka = *(const uint4*)(Kg + grow);
                kb = *(const uint4*)(Kg + grow + 8);
                va = *(const uint4*)(Vg + vrow + (st + 1) * 64 + ec);
                vb = *(const uint4*)(Vg + vrow + (st + 1) * 64 + ec + 8);
            }

            float sv[4][4];
            #pragma unroll
            for (int nt = 0; nt < 4; nt++) {
                bfrag kb0 = *(const bfrag*)&Ks[nt * 16 + lo16][quad * 8];
                bfrag kb1 = *(const bfrag*)&Ks[nt * 16 + lo16][32 + quad * 8];
                f32x4 cs = {0.f, 0.f, 0.f, 0.f};
                cs = __builtin_amdgcn_mfma_f32_16x16x32_bf16(qa0, kb0, cs, 0, 0, 0);
                cs = __builtin_amdgcn_mfma_f32_16x16x32_bf16(qa1, kb1, cs, 0, 0, 0);
                #pragma unroll
                for (int r = 0; r < 4; r++) sv[nt][r] = cs[r] * 0.125f;
            }
            if (st == qt) {
                #pragma unroll
                for (int nt = 0; nt < 4; nt++)
                    #pragma unroll
                    for (int r = 0; r < 4; r++)
                        if (nt * 16 + lo16 > w * 16 + quad * 4 + r) sv[nt][r] = -3e38f;
            }
            #pragma unroll
            for (int r = 0; r < 4; r++) {
                float m = fmaxf(fmaxf(sv[0][r], sv[1][r]), fmaxf(sv[2][r], sv[3][r]));
                #pragma unroll
                for (int off = 1; off < 16; off <<= 1)
                    m = fmaxf(m, __shfl_xor(m, off, 64));
                float mnew = fmaxf(m_r[r], m);
                float alpha = __expf(m_r[r] - mnew);
                m_r[r] = mnew;
                float s = 0.f;
                #pragma unroll
                for (int nt = 0; nt < 4; nt++) {
                    sv[nt][r] = __expf(sv[nt][r] - mnew);
                    s += sv[nt][r];
                }
                #pragma unroll
                for (int off = 1; off < 16; off <<= 1)
                    s += __shfl_xor(s, off, 64);
                l_r[r] = l_r[r] * alpha + s;
                #pragma unroll
                for (int et = 0; et < 4; et++) oacc[et][r] *= alpha;
            }
            #pragma unroll
            for (int nt = 0; nt < 4; nt++)
                #pragma unroll
                for (int r = 0; r < 4; r++)
                    Ps[w][quad * 4 + r][nt * 16 + lo16] = f2b(sv[nt][r]);
            bfrag pa0 = *(const bfrag*)&Ps[w][lo16][quad * 8];
            bfrag pa1 = *(const bfrag*)&Ps[w][lo16][32 + quad * 8];
            #pragma unroll
            for (int et = 0; et < 4; et++) {
                bfrag vb0 = *(const bfrag*)&Vt[et * 16 + lo16][quad * 8];
                bfrag vb1 = *(const bfrag*)&Vt[et * 16 + lo16][32 + quad * 8];
                oacc[et] = __builtin_amdgcn_mfma_f32_16x16x32_bf16(pa0, vb0, oacc[et], 0, 0, 0);
                oacc[et] = __builtin_amdgcn_mfma_f32_16x16x32_bf16(pa1, vb1, oacc[et], 0, 0, 0);
            }
            __syncthreads();
        }
        #pragma unroll
        for (int r = 0; r < 4; r++) {
            float rl = 1.f / l_r[r];
            const int row = q0 + w * 16 + quad * 4 + r;
            u16* orow = Q + (size_t)(b * T_ + row) * 1024;
            #pragma unroll
            for (int et = 0; et < 4; et++)
                orow[swz(row, h * 64 + et * 16 + lo16)] = f2b(oacc[et][r] * rl);
        }
    }
}

// LN(src bf16)*g + be + resid(fp32). WF32=1 -> fp32 dstf, else bf16 dstb
// (OSWZ: bf16 output written pre-swizzled for cgemm A consumption).
template <int WF32, int OSWZ>
__global__ __launch_bounds__(256) void ln_kernel(
    const u16* __restrict__ src, const float* __restrict__ resid,
    const float* __restrict__ g, const float* __restrict__ be,
    u16* __restrict__ dstb, float* __restrict__ dstf)
{
    const int r = blockIdx.x;
    const int tid = threadIdx.x;
    uint2 raw = ((const uint2*)(src + (size_t)r * D_))[tid];
    float y[4];
    y[0] = __uint_as_float(raw.x << 16);
    y[1] = __uint_as_float(raw.x & 0xffff0000u);
    y[2] = __uint_as_float(raw.y << 16);
    y[3] = __uint_as_float(raw.y & 0xffff0000u);
    float s = y[0] + y[1] + y[2] + y[3];
    float sq = y[0]*y[0] + y[1]*y[1] + y[2]*y[2] + y[3]*y[3];
    #pragma unroll
    for (int o = 32; o > 0; o >>= 1) {
        s += __shfl_down(s, o, 64);
        sq += __shfl_down(sq, o, 64);
    }
    __shared__ float rs[4], rq[4];
    if ((tid & 63) == 0) { rs[tid >> 6] = s; rq[tid >> 6] = sq; }
    __syncthreads();
    const float S = rs[0] + rs[1] + rs[2] + rs[3];
    const float Qm = rq[0] + rq[1] + rq[2] + rq[3];
    const float mu = S * (1.f / (float)D_);
    const float var = fmaxf(Qm * (1.f / (float)D_) - mu * mu, 0.f);
    const float rstd = rsqrtf(var + EPS_);
    const int c = tid * 4;
    #pragma unroll
    for (int i = 0; i < 4; i++) {
        y[i] = (y[i] - mu) * rstd * g[c + i] + be[c + i]
             + resid[(size_t)r * D_ + c + i];
    }
    if constexpr (WF32) {
        float4 o = {y[0], y[1], y[2], y[3]};
        ((float4*)(dstf + (size_t)r * D_))[tid] = o;
    } else {
        uint2 o;
        o.x = (unsigned)f2b(y[0]) | ((unsigned)f2b(y[1]) << 16);
        o.y = (unsigned)f2b(y[2]) | ((unsigned)f2b(y[3]) << 16);
        const int cs = OSWZ ? swz(r, c) : c;
        *(uint2*)(dstb + (size_t)r * D_ + cs) = o;
    }
}

extern "C" void kernel_launch(void* const* d_in, const int* in_sizes, int n_in,
                              void* d_out, int out_size, void* d_ws, size_t ws_size,
                              hipStream_t stream)
{
    const float* emb = (const float*)d_in[0];
    const float* Wq  = (const float*)d_in[1];
    const float* Wk  = (const float*)d_in[2];
    const float* Wv  = (const float*)d_in[3];
    const float* Wo  = (const float*)d_in[4];
    const float* bo  = (const float*)d_in[5];
    const float* W1  = (const float*)d_in[6];
    const float* b1  = (const float*)d_in[7];
    const float* W2  = (const float*)d_in[8];
    const float* b2  = (const float*)d_in[9];
    const float* g1  = (const float*)d_in[10];
    const float* be1 = (const float*)d_in[11];
    const float* g2  = (const float*)d_in[12];
    const float* be2 = (const float*)d_in[13];

    u16* WS = (u16*)d_ws;       // 4M u16
    u16* DO = (u16*)d_out;      // 8M u16

    const size_t M1 = 1024 * 1024;
    u16* WkvT = WS;                      // [2048][1024] bf16 swz (4MB)
    u16* Q    = WS;                      // natural (over dead WkvT)
    u16* Kb   = DO;                      // [0,4M) natural
    u16* Vb   = DO + 4 * M1;             // [4M,8M) V^T [b][h][64][2048]
    u16* O    = WS;                      // fattn writes O (swz) over Q
    u16* WoT  = DO;                      // [0,1M) swz, over dead K
    u16* P    = DO + 4 * M1;             // [4M,8M) natural, over dead V
    u16* Af   = DO;                      // [0,4M) swz, over dead WoT
    u16* Hc   = DO + 4 * M1;             // [4M,6M) [2048][1024] swz
    u16* W1T  = DO + 6 * M1;             // [6M,7M) swz
    u16* W2T  = DO + 7 * M1;             // [7M,8M) swz
    u16* F    = WS;                      // natural, over dead O
    float* outf = (float*)d_out;

    const dim3 blk(256);

    // 1) Wk,Wv -> WkvT bf16 swz (one launch)
    tcvt_kv<<<dim3(1, 16, 32), blk, 0, stream>>>(Wk, Wv, WkvT);
    // 2) K,V = emb @ WkvT^T  (A fp32, split; V written TRANSPOSED)
    cgemm<1, 1, 0, 0, 4, 0, 0, 1><<<dim3(16, 32), blk, 0, stream>>>(
        emb, 1024, WkvT, Kb, Vb, 1024, 1024, nullptr, 0);
    // 3) Q = emb @ Wq (old fp32-staging path, natural)
    mgemm<1, 1, 0, 0><<<dim3(8, 32), blk, 0, stream>>>(
        emb, Wq, Wq, Wq, Q, nullptr, nullptr, 0, 0, 0, nullptr, 0);
    // 4) flash attention (R13 body + V^T staging), O (swz) over Q
    fattn_kernel<<<Bq_ * H_ * 16, blk, 0, stream>>>(Q, Kb, Vb);
    // 5) Wo -> WoT bf16 swz (over dead K)
    tcvt<<<dim3(16, 16), blk, 0, stream>>>(Wo, 1024, 0, 0, WoT, 1024, 0);
    // 6) P = O @ WoT^T + bo (natural C, over dead V; WAVE NT=4)
    cgemm<0, 0, 0, 0, 4, 0, 1, 0><<<dim3(8, 32), blk, 0, stream>>>(
        O, 1024, WoT, P, nullptr, 1024, 1024, bo, 0);
    // 7) Af = LN(P) + emb (swz out)
    ln_kernel<0, 1><<<N_, blk, 0, stream>>>(P, emb, g1, be1, Af, nullptr);
    // 8) FFN: 4 hidden chunks x 2 row-halves; NT=2 WAVE, 256-block grids
    for (int c = 0; c < 4; c++) {
        tcvt_ffn<<<dim3(16, 16, 2), blk, 0, stream>>>(W1, W2, c, W1T, W2T);
        for (int rh = 0; rh < 2; rh++) {
            u16* Afh = Af + (size_t)rh * 2048 * 1024;
            u16* Fh  = F  + (size_t)rh * 2048 * 1024;
            cgemm<0, 0, 1, 0, 2, 1, 1, 0><<<dim3(8, 32), blk, 0, stream>>>(
                Afh, 1024, W1T, Hc, nullptr, 1024, 1024, b1, c * 1024);
            if (c == 0) {
                cgemm<0, 0, 0, 0, 2, 0, 1, 0><<<dim3(8, 32), blk, 0, stream>>>(
                    Hc, 1024, W2T, Fh, nullptr, 1024, 1024, b2, 0);
            } else {
                cgemm<0, 0, 0, 1, 2, 0, 1, 0><<<dim3(8, 32), blk, 0, stream>>>(
                    Hc, 1024, W2T, Fh, nullptr, 1024, 1024, nullptr, 0);
            }
        }
    }
    // 9) out = fp32(LN(F) + emb)
    ln_kernel<1, 0><<<N_, blk, 0, stream>>>(F, emb, g2, be2, nullptr, outf);
}